// Round 2
// baseline (903.001 us; speedup 1.0000x reference)
//
#include <hip/hip_runtime.h>

typedef _Float16 f16;
typedef __attribute__((ext_vector_type(8))) _Float16 f16x8;
typedef __attribute__((ext_vector_type(4))) _Float16 f16x4v;
typedef __attribute__((ext_vector_type(4))) float f32x4;

#define B_ 16
#define S_ 2048
#define H_ 1024
#define D_ 512
#define LDK 72

// ---------------- fp32 -> fp16 convert (hidden states) ----------------
__global__ __launch_bounds__(256) void cvt_hs_kernel(const float4* __restrict__ in,
                                                     f16x4v* __restrict__ out) {
  long long i = (long long)blockIdx.x * 256 + threadIdx.x;  // 8,388,608 total
  float4 v = in[i];
  f16x4v o = {(f16)v.x, (f16)v.y, (f16)v.z, (f16)v.w};
  out[i] = o;
}

// ---------------- Wt (1536 x 1024) fp16: rows 0-511 Wq^T, 512-1023 Wk^T, 1024-1535 W1^T
__global__ __launch_bounds__(256) void build_wt_kernel(const float* __restrict__ Wq,
                                                       const float* __restrict__ Wk,
                                                       const float* __restrict__ W1,
                                                       f16* __restrict__ Wt) {
  int i = blockIdx.x * 256 + threadIdx.x;  // 1536*1024
  int n = i >> 10;
  int k = i & 1023;
  const float* src = (n < 512) ? Wq : ((n < 1024) ? Wk : W1);
  int nn = n & 511;
  Wt[i] = (f16)src[k * 512 + nn];
}

__global__ __launch_bounds__(256) void build_bias_kernel(const float* __restrict__ bq,
                                                         const float* __restrict__ bk,
                                                         float* __restrict__ bias) {
  int i = blockIdx.x * 256 + threadIdx.x;
  if (i < 1024) bias[i] = (i < 512) ? bq[i] : bk[i - 512];
}

// ---------------- per-batch valid length ----------------
__global__ __launch_bounds__(256) void lens_kernel(const int* __restrict__ mask,
                                                   int* __restrict__ lens) {
  int b = blockIdx.x;
  int tid = threadIdx.x;
  int s = 0;
  for (int c = tid; c < S_; c += 256) s += mask[b * S_ + c];
  __shared__ int r[256];
  r[tid] = s;
  __syncthreads();
  for (int o = 128; o > 0; o >>= 1) {
    if (tid < o) r[tid] += r[tid + o];
    __syncthreads();
  }
  if (tid == 0) lens[b] = r[0];
}

// ---------------- GEMM: C[m][n] = scale * (sum_k A[m][k]*Bt[n][k]) + bias[n]
// 128x128 tile, BK=64, mfma_f32_16x16x32_f16.  mode: 0=f32 store, 1=f16 store,
// 2=f16 store transposed into vt[b][d][t] (b = row>>11, t = row&2047).
__global__ __launch_bounds__(256) void gemm_bt(
    const f16* __restrict__ A, const f16* __restrict__ Bm, void* __restrict__ Cout,
    int K, int lda, int ldb, int ldc,
    long long sA, long long sB, long long sC,
    float scale, const float* __restrict__ bias, int mode) {
  const int bz = blockIdx.z;
  A += (long long)bz * sA;
  Bm += (long long)bz * sB;

  __shared__ f16 As[128 * LDK];
  __shared__ f16 Bs[128 * LDK];

  const int m0 = blockIdx.y * 128;
  const int n0 = blockIdx.x * 128;
  const int tid = threadIdx.x;
  const int lane = tid & 63;
  const int wid = tid >> 6;
  const int wm = wid & 1, wn = wid >> 1;

  f32x4 acc[4][4] = {};

  const int sr = tid >> 3;       // 0..31
  const int sc = (tid & 7) * 8;  // 0..56

  for (int k0 = 0; k0 < K; k0 += 64) {
#pragma unroll
    for (int it = 0; it < 4; ++it) {
      const int row = it * 32 + sr;
      f16x8 va = *(const f16x8*)(A + (long long)(m0 + row) * lda + k0 + sc);
      f16x8 vb = *(const f16x8*)(Bm + (long long)(n0 + row) * ldb + k0 + sc);
      *(f16x8*)(As + row * LDK + sc) = va;
      *(f16x8*)(Bs + row * LDK + sc) = vb;
    }
    __syncthreads();

#pragma unroll
    for (int kk = 0; kk < 64; kk += 32) {
      const int kb = kk + ((lane >> 4) << 3);
      f16x8 af[4], bf[4];
#pragma unroll
      for (int i = 0; i < 4; ++i)
        af[i] = *(const f16x8*)(As + (wm * 64 + i * 16 + (lane & 15)) * LDK + kb);
#pragma unroll
      for (int j = 0; j < 4; ++j)
        bf[j] = *(const f16x8*)(Bs + (wn * 64 + j * 16 + (lane & 15)) * LDK + kb);
#pragma unroll
      for (int i = 0; i < 4; ++i)
#pragma unroll
        for (int j = 0; j < 4; ++j)
          acc[i][j] = __builtin_amdgcn_mfma_f32_16x16x32_f16(af[i], bf[j], acc[i][j], 0, 0, 0);
    }
    __syncthreads();
  }

  const long long cb = (long long)bz * sC;
  const int lr = ((lane >> 4) << 2);
  const int lc = lane & 15;
#pragma unroll
  for (int i = 0; i < 4; ++i) {
#pragma unroll
    for (int j = 0; j < 4; ++j) {
      const int col = n0 + wn * 64 + j * 16 + lc;
      const float bv = bias ? bias[col] : 0.0f;
      if (mode == 2) {
        const int rowb = m0 + wm * 64 + i * 16 + lr;  // 4 consecutive tokens
        const int b = rowb >> 11, t = rowb & 2047;
        f16x4v pk;
#pragma unroll
        for (int r = 0; r < 4; ++r) pk[r] = (f16)(acc[i][j][r] * scale + bv);
        *(f16x4v*)((f16*)Cout + ((long long)b << 20) + (long long)col * 2048 + t) = pk;
      } else {
#pragma unroll
        for (int r = 0; r < 4; ++r) {
          const int row = m0 + wm * 64 + i * 16 + lr + r;
          float v = acc[i][j][r] * scale + bv;
          if (mode == 1)
            ((f16*)Cout)[cb + (long long)row * ldc + col] = (f16)v;
          else
            ((float*)Cout)[cb + (long long)row * ldc + col] = v;
        }
      }
    }
  }
}

// ---------------- in-place row softmax over valid prefix (fp16 scores -> fp16 probs)
__global__ __launch_bounds__(256) void softmax_rows_kernel(f16* __restrict__ sc,
                                                           const int* __restrict__ lens) {
  const int row = blockIdx.x;
  const int b = row >> 11;
  const int len = lens[b];
  f16* p = sc + (long long)row * S_;
  const int tid = threadIdx.x;
  __shared__ float r[256];

  float m = -1e30f;
  for (int c = tid; c < len; c += 256) m = fmaxf(m, (float)p[c]);
  r[tid] = m;
  __syncthreads();
  for (int o = 128; o > 0; o >>= 1) {
    if (tid < o) r[tid] = fmaxf(r[tid], r[tid + o]);
    __syncthreads();
  }
  m = r[0];
  __syncthreads();

  float s = 0.0f;
  for (int c = tid; c < len; c += 256) s += __expf((float)p[c] - m);
  r[tid] = s;
  __syncthreads();
  for (int o = 128; o > 0; o >>= 1) {
    if (tid < o) r[tid] += r[tid + o];
    __syncthreads();
  }
  const float inv = 1.0f / r[0];

  for (int c = tid; c < S_; c += 256) {
    float v = (c < len) ? __expf((float)p[c] - m) * inv : 0.0f;
    p[c] = (f16)v;
  }
}

// ---------------- LayerNorm + ReLU + dot(W2) -> ts (fp32) and out_ts (fp32, masked)
__global__ __launch_bounds__(256) void ln_score_kernel(
    const float* __restrict__ h, const int* __restrict__ lens,
    const float* __restrict__ g, const float* __restrict__ bt,
    const float* __restrict__ W2, const float* __restrict__ b2,
    float* __restrict__ ts, float* __restrict__ out_ts) {
  const int token = blockIdx.x;
  const float* hp = h + (long long)token * D_;
  const int tid = threadIdx.x;
  float x0 = hp[tid], x1 = hp[tid + 256];
  __shared__ float r1[256], r2[256];
  r1[tid] = x0 + x1;
  r2[tid] = x0 * x0 + x1 * x1;
  __syncthreads();
  for (int o = 128; o > 0; o >>= 1) {
    if (tid < o) { r1[tid] += r1[tid + o]; r2[tid] += r2[tid + o]; }
    __syncthreads();
  }
  const float mu = r1[0] * (1.0f / D_);
  const float var = r2[0] * (1.0f / D_) - mu * mu;
  const float rs = rsqrtf(var + 1e-5f);
  float y0 = fmaxf((x0 - mu) * rs * g[tid] + bt[tid], 0.0f);
  float y1 = fmaxf((x1 - mu) * rs * g[tid + 256] + bt[tid + 256], 0.0f);
  float d = y0 * W2[tid] + y1 * W2[tid + 256];
  __syncthreads();
  r1[tid] = d;
  __syncthreads();
  for (int o = 128; o > 0; o >>= 1) {
    if (tid < o) r1[tid] += r1[tid + o];
    __syncthreads();
  }
  if (tid == 0) {
    float v = r1[0] + b2[0];
    ts[token] = v;
    const int b = token >> 11, s = token & (S_ - 1);
    out_ts[token] = (s < lens[b]) ? v : -10000.0f;
  }
}

// ---------------- rationale: cumsum + window argmax (ref tie-break) + span mask
__global__ __launch_bounds__(256) void rationale_kernel(
    const float* __restrict__ ts, const int* __restrict__ lens,
    float* __restrict__ out_rat, int* __restrict__ span) {
  const int b = blockIdx.x;
  const int tid = threadIdx.x;
  const int len = lens[b];
  __shared__ float cum[S_];
  __shared__ float rbest[256];
  __shared__ int ridx[256];

  for (int s = tid; s < S_; s += 256)
    cum[s] = (s < len) ? ts[b * S_ + s] : -10000.0f;
  __syncthreads();
  if (tid == 0) {  // sequential fp32 cumsum, matches np/jax fp32 semantics
    float a = 0.0f;
    for (int s = 0; s < S_; ++s) { a += cum[s]; cum[s] = a; }
  }
  __syncthreads();

  float best = -3.4e38f;
  int bidx = 0x7fffffff;
  for (int idx = tid; idx < 18 * S_; idx += 256) {
    const int l = idx >> 11;
    const int s = idx & (S_ - 1);
    const int L = l + 3;
    if (L <= len && s <= len - L) {
      // NOTE: reference uses the PREFIX sum cum[s+L-1]/L (not the window sum)
      const float gv = cum[s + L - 1] / (float)L + 0.01f * ((float)L / 20.0f);
      if (gv > best) { best = gv; bidx = idx; }  // strict >: smallest idx within thread
    }
  }
  rbest[tid] = best;
  ridx[tid] = bidx;
  __syncthreads();
  for (int o = 128; o > 0; o >>= 1) {
    if (tid < o) {
      if (rbest[tid + o] > rbest[tid] ||
          (rbest[tid + o] == rbest[tid] && ridx[tid + o] < ridx[tid])) {
        rbest[tid] = rbest[tid + o];
        ridx[tid] = ridx[tid + o];
      }
    }
    __syncthreads();
  }
  const int bi = ridx[0];
  int start, sl;
  if (len <= 3) { start = 0; sl = len; }  // short-circuit case
  else { start = bi & (S_ - 1); sl = (bi >> 11) + 3; }
  if (tid == 0) { span[2 * b] = start; span[2 * b + 1] = sl; }
  for (int s = tid; s < S_; s += 256)
    out_rat[b * S_ + s] = (s >= start && s < start + sl) ? 1.0f : 0.0f;
}

// ---------------- token_probs: softmax over masked token scores (per batch) ----------------
__global__ __launch_bounds__(256) void tprobs_kernel(const float* __restrict__ ts,
                                                     const int* __restrict__ lens,
                                                     float* __restrict__ out) {
  const int b = blockIdx.x;
  const int tid = threadIdx.x;
  const int len = lens[b];
  const float* p = ts + b * S_;
  __shared__ float r[256];
  float m = -1e30f;
  for (int c = tid; c < len; c += 256) m = fmaxf(m, p[c]);
  r[tid] = m;
  __syncthreads();
  for (int o = 128; o > 0; o >>= 1) {
    if (tid < o) r[tid] = fmaxf(r[tid], r[tid + o]);
    __syncthreads();
  }
  m = r[0];
  __syncthreads();
  float s = 0.0f;
  for (int c = tid; c < len; c += 256) s += expf(p[c] - m);
  r[tid] = s;
  __syncthreads();
  for (int o = 128; o > 0; o >>= 1) {
    if (tid < o) r[tid] += r[tid + o];
    __syncthreads();
  }
  const float inv = 1.0f / r[0];
  for (int c = tid; c < S_; c += 256)
    out[b * S_ + c] = (c < len) ? expf(p[c] - m) * inv : 0.0f;
}

// ---------------- attended = hs * rationale (fp32 out) ----------------
__global__ __launch_bounds__(256) void attended_kernel(const float4* __restrict__ hs,
                                                       const int* __restrict__ span,
                                                       float4* __restrict__ out) {
  long long i = (long long)blockIdx.x * 256 + threadIdx.x;  // over B*S*H/4
  const int token = (int)(i >> 8);  // / (H_/4)
  const int b = token >> 11;
  const int s = token & (S_ - 1);
  const int st = span[2 * b], ln = span[2 * b + 1];
  float4 v = {0.0f, 0.0f, 0.0f, 0.0f};
  if (s >= st && s < st + ln) v = hs[i];
  out[i] = v;
}

// ---------------- pooled = sum over span / (len + 1e-6) (fp32 out) ----------------
__global__ __launch_bounds__(256) void pooled_kernel(const float* __restrict__ hs,
                                                     const int* __restrict__ span,
                                                     float* __restrict__ out) {
  const int b = blockIdx.x;
  const int tid = threadIdx.x;
  const int st = span[2 * b], ln = span[2 * b + 1];
  const float inv = 1.0f / ((float)ln + 1e-6f);
  for (int h = tid; h < H_; h += 256) {
    float s = 0.0f;
    for (int t = st; t < st + ln; ++t)
      s += hs[(long long)(b * S_ + t) * H_ + h];
    out[b * H_ + h] = s * inv;
  }
}

// ---------------- launch ----------------
extern "C" void kernel_launch(void* const* d_in, const int* in_sizes, int n_in,
                              void* d_out, int out_size, void* d_ws, size_t ws_size,
                              hipStream_t stream) {
  const float* hs = (const float*)d_in[0];
  const int* amask = (const int*)d_in[1];
  const float* Wq = (const float*)d_in[2];
  const float* bq = (const float*)d_in[3];
  const float* Wk = (const float*)d_in[4];
  const float* bk = (const float*)d_in[5];
  const float* W1 = (const float*)d_in[6];
  const float* b1 = (const float*)d_in[7];
  const float* ln_g = (const float*)d_in[8];
  const float* ln_b = (const float*)d_in[9];
  const float* W2 = (const float*)d_in[10];
  const float* b2 = (const float*)d_in[11];

  float* out = (float*)d_out;  // reference outputs are float32
  char* ws = (char*)d_ws;

  // workspace layout (bytes)
  const long long off_hs16 = 0;           // 67,108,864  (fp16 hs; later reused as fp32 h)
  const long long off_qk = 67108864;      // 67,108,864  (32768 x 1024 fp16: [Q|K])
  const long long off_vt = 134217728;     // 33,554,432  (vt[b][d][t] fp16)
  const long long off_wt = 167772160;     // 3,145,728
  const long long off_bias = 170917888;   // 8,192
  const long long off_ts = 170926080;     // 131,072
  const long long off_lens = 171057152;   // 64
  const long long off_span = 171057216;   // 192
  const long long off_scores = 171057408; // nb * 8,388,608

  f16* hs16 = (f16*)(ws + off_hs16);
  float* hbuf = (float*)(ws + off_hs16);  // alias: hs16 dead after QK/V GEMMs
  f16* qk16 = (f16*)(ws + off_qk);
  f16* vt = (f16*)(ws + off_vt);
  f16* Wt = (f16*)(ws + off_wt);
  float* bias_qk = (float*)(ws + off_bias);
  float* ts = (float*)(ws + off_ts);
  int* lens = (int*)(ws + off_lens);
  int* span = (int*)(ws + off_span);
  f16* scores = (f16*)(ws + off_scores);

  // adaptive batch-chunking of the scores buffer to fit ws_size
  const long long SC_PER_B = (long long)S_ * S_ * 2;  // 8,388,608 B
  int nb = 16;
  while (nb > 1 && off_scores + (long long)nb * SC_PER_B > (long long)ws_size) nb >>= 1;

  // output sections (fp32 elements)
  float* out_ts = out;                  // 16*2048
  float* out_rat = out + 32768;         // 16*2048
  float* out_tp = out + 65536;          // 16*2048
  float4* out_att = (float4*)(out + 98304);  // 16*2048*1024
  float* out_pool = out + 33652736;     // 16*1024

  hipLaunchKernelGGL(lens_kernel, dim3(B_), dim3(256), 0, stream, amask, lens);
  hipLaunchKernelGGL(cvt_hs_kernel, dim3(32768), dim3(256), 0, stream,
                     (const float4*)hs, (f16x4v*)hs16);
  hipLaunchKernelGGL(build_wt_kernel, dim3(6144), dim3(256), 0, stream, Wq, Wk, W1, Wt);
  hipLaunchKernelGGL(build_bias_kernel, dim3(4), dim3(256), 0, stream, bq, bk, bias_qk);

  // QK: (32768 x 1024) = hs16 @ Wt[0:1024]^T  (+[bq|bk])
  hipLaunchKernelGGL(gemm_bt, dim3(8, 256, 1), dim3(256), 0, stream,
                     hs16, Wt, (void*)qk16, 1024, 1024, 1024, 1024,
                     0LL, 0LL, 0LL, 1.0f, bias_qk, 1);
  // V: (32768 x 512) = hs16 @ Wt[1024:1536]^T + b1, stored transposed into vt[b][d][t]
  hipLaunchKernelGGL(gemm_bt, dim3(4, 256, 1), dim3(256), 0, stream,
                     hs16, Wt + 1024 * 1024, (void*)vt, 1024, 1024, 1024, 2048,
                     0LL, 0LL, 0LL, 1.0f, b1, 2);

  const int chunks = 16 / nb;
  for (int c = 0; c < chunks; ++c) {
    const int b0 = c * nb;
    // scores: per batch (2048x2048) = Q @ K^T / sqrt(512), fp16
    hipLaunchKernelGGL(gemm_bt, dim3(16, 16, nb), dim3(256), 0, stream,
                       qk16 + (long long)b0 * S_ * 1024,
                       qk16 + (long long)b0 * S_ * 1024 + 512,
                       (void*)scores, 512, 1024, 1024, 2048,
                       (long long)S_ * 1024, (long long)S_ * 1024, (long long)S_ * S_,
                       0.044194173824159216f /* 1/sqrt(512) */, (const float*)nullptr, 1);
    hipLaunchKernelGGL(softmax_rows_kernel, dim3(nb * S_), dim3(256), 0, stream,
                       scores, lens + b0);
    // h: per batch (2048x512) = P @ V (b1 already folded into V; rows of P sum to 1)
    hipLaunchKernelGGL(gemm_bt, dim3(4, 16, nb), dim3(256), 0, stream,
                       scores, vt + ((long long)b0 << 20),
                       (void*)(hbuf + (long long)b0 * S_ * D_), 2048, 2048, 2048, 512,
                       (long long)S_ * S_, 1LL << 20, (long long)S_ * D_,
                       1.0f, (const float*)nullptr, 0);
  }

  hipLaunchKernelGGL(ln_score_kernel, dim3(B_ * S_), dim3(256), 0, stream,
                     hbuf, lens, ln_g, ln_b, W2, b2, ts, out_ts);

  hipLaunchKernelGGL(rationale_kernel, dim3(B_), dim3(256), 0, stream,
                     ts, lens, out_rat, span);
  hipLaunchKernelGGL(tprobs_kernel, dim3(B_), dim3(256), 0, stream, ts, lens, out_tp);
  hipLaunchKernelGGL(attended_kernel, dim3(32768), dim3(256), 0, stream,
                     (const float4*)hs, span, out_att);
  hipLaunchKernelGGL(pooled_kernel, dim3(B_), dim3(256), 0, stream, hs, span, out_pool);
}

// Round 3
// 754.978 us; speedup vs baseline: 1.1961x; 1.1961x over previous
//
#include <hip/hip_runtime.h>

typedef _Float16 f16;
typedef __attribute__((ext_vector_type(8))) _Float16 f16x8;
typedef __attribute__((ext_vector_type(4))) _Float16 f16x4v;
typedef __attribute__((ext_vector_type(4))) float f32x4;

#define B_ 16
#define S_ 2048
#define H_ 1024
#define D_ 512

// async 16B global->LDS; lds dest is wave-uniform base + lane*16
__device__ __forceinline__ void gload16(const f16* g, f16* l) {
  __builtin_amdgcn_global_load_lds(
      (const __attribute__((address_space(1))) unsigned int*)g,
      (__attribute__((address_space(3))) unsigned int*)l, 16, 0, 0);
}

// ---------------- fp32 -> fp16 convert (hidden states) ----------------
__global__ __launch_bounds__(256) void cvt_hs_kernel(const float4* __restrict__ in,
                                                     f16x4v* __restrict__ out) {
  long long i = (long long)blockIdx.x * 256 + threadIdx.x;  // 8,388,608 total
  float4 v = in[i];
  f16x4v o = {(f16)v.x, (f16)v.y, (f16)v.z, (f16)v.w};
  out[i] = o;
}

// ---------------- Wt (1536 x 1024) fp16: rows 0-511 Wq^T, 512-1023 Wk^T, 1024-1535 W1^T
__global__ __launch_bounds__(256) void build_wt_kernel(const float* __restrict__ Wq,
                                                       const float* __restrict__ Wk,
                                                       const float* __restrict__ W1,
                                                       f16* __restrict__ Wt) {
  int i = blockIdx.x * 256 + threadIdx.x;  // 1536*1024
  int n = i >> 10;
  int k = i & 1023;
  const float* src = (n < 512) ? Wq : ((n < 1024) ? Wk : W1);
  int nn = n & 511;
  Wt[i] = (f16)src[k * 512 + nn];
}

__global__ __launch_bounds__(256) void build_bias_kernel(const float* __restrict__ bq,
                                                         const float* __restrict__ bk,
                                                         float* __restrict__ bias) {
  int i = blockIdx.x * 256 + threadIdx.x;
  if (i < 1024) bias[i] = (i < 512) ? bq[i] : bk[i - 512];
}

// ---------------- per-batch valid length ----------------
__global__ __launch_bounds__(256) void lens_kernel(const int* __restrict__ mask,
                                                   int* __restrict__ lens) {
  int b = blockIdx.x;
  int tid = threadIdx.x;
  int s = 0;
  for (int c = tid; c < S_; c += 256) s += mask[b * S_ + c];
  __shared__ int r[256];
  r[tid] = s;
  __syncthreads();
  for (int o = 128; o > 0; o >>= 1) {
    if (tid < o) r[tid] += r[tid + o];
    __syncthreads();
  }
  if (tid == 0) lens[b] = r[0];
}

// ---------------- GEMM: C[m][n] = scale * (sum_k A[m][k]*Bt[n][k]) + bias[n]
// 128x128 tile, BK=64, mfma_f32_16x16x32_f16, async global_load_lds staging,
// XOR-swizzled LDS layout (col-group ^ (row&7)) to kill ds_read bank conflicts.
// mode: 0=f32 store, 1=f16 store, 2=f16 store transposed into vt[b][d][t].
// lflags: 1 = len from lens[m0>>11], skip block if (m0&2047) >= len  (QKV gemms)
//         2 = len from lens[bz], skip if (m0&2047) >= len            (scores/PV)
//         4 = skip if n0 >= len                                      (scores)
//         8 = clamp K to ceil64(len)                                 (PV)
__global__ __launch_bounds__(256) void gemm_bt(
    const f16* __restrict__ A, const f16* __restrict__ Bm, void* __restrict__ Cout,
    int K, int lda, int ldb, int ldc,
    long long sA, long long sB, long long sC,
    float scale, const float* __restrict__ bias, int mode,
    const int* __restrict__ lens, int lflags) {
  const int bz = blockIdx.z;
  const int m0 = blockIdx.y * 128;
  const int n0 = blockIdx.x * 128;

  int Keff = K;
  if (lflags) {
    const int len = lens[(lflags & 1) ? (m0 >> 11) : bz];
    if ((lflags & 3) && (m0 & 2047) >= len) return;
    if ((lflags & 4) && n0 >= len) return;
    if (lflags & 8) { int kl = (len + 63) & ~63; Keff = kl < K ? kl : K; }
  }

  A += (long long)bz * sA;
  Bm += (long long)bz * sB;

  __shared__ f16 As[128 * 64];
  __shared__ f16 Bs[128 * 64];

  const int tid = threadIdx.x;
  const int lane = tid & 63;
  const int wid = tid >> 6;
  const int wm = wid & 1, wn = wid >> 1;

  f32x4 acc[4][4] = {};

  const int lr8 = lane >> 3;  // row within 8-row staging group
  const int sg = lane & 7;    // LDS slot col-group

  for (int k0 = 0; k0 < Keff; k0 += 64) {
#pragma unroll
    for (int it = 0; it < 4; ++it) {
      const int r0 = it * 32 + wid * 8;
      const int r = r0 + lr8;
      const int cg = sg ^ (r & 7);  // source col-group for swizzled slot
      gload16(A + (long long)(m0 + r) * lda + k0 + cg * 8, As + r0 * 64);
      gload16(Bm + (long long)(n0 + r) * ldb + k0 + cg * 8, Bs + r0 * 64);
    }
    __syncthreads();

#pragma unroll
    for (int kk = 0; kk < 64; kk += 32) {
      const int cg = (kk >> 3) + (lane >> 4);
      f16x8 af[4], bf[4];
#pragma unroll
      for (int i = 0; i < 4; ++i) {
        const int row = wm * 64 + i * 16 + (lane & 15);
        af[i] = *(const f16x8*)(As + row * 64 + ((cg ^ (row & 7)) << 3));
      }
#pragma unroll
      for (int j = 0; j < 4; ++j) {
        const int row = wn * 64 + j * 16 + (lane & 15);
        bf[j] = *(const f16x8*)(Bs + row * 64 + ((cg ^ (row & 7)) << 3));
      }
#pragma unroll
      for (int i = 0; i < 4; ++i)
#pragma unroll
        for (int j = 0; j < 4; ++j)
          acc[i][j] = __builtin_amdgcn_mfma_f32_16x16x32_f16(af[i], bf[j], acc[i][j], 0, 0, 0);
    }
    __syncthreads();
  }

  const long long cb = (long long)bz * sC;
  const int lr = ((lane >> 4) << 2);
  const int lc = lane & 15;
#pragma unroll
  for (int i = 0; i < 4; ++i) {
#pragma unroll
    for (int j = 0; j < 4; ++j) {
      const int col = n0 + wn * 64 + j * 16 + lc;
      const float bv = bias ? bias[col] : 0.0f;
      if (mode == 2) {
        const int rowb = m0 + wm * 64 + i * 16 + lr;  // 4 consecutive tokens
        const int b = rowb >> 11, t = rowb & 2047;
        f16x4v pk;
#pragma unroll
        for (int r = 0; r < 4; ++r) pk[r] = (f16)(acc[i][j][r] * scale + bv);
        *(f16x4v*)((f16*)Cout + ((long long)b << 20) + (long long)col * 2048 + t) = pk;
      } else {
#pragma unroll
        for (int r = 0; r < 4; ++r) {
          const int row = m0 + wm * 64 + i * 16 + lr + r;
          float v = acc[i][j][r] * scale + bv;
          if (mode == 1)
            ((f16*)Cout)[cb + (long long)row * ldc + col] = (f16)v;
          else
            ((float*)Cout)[cb + (long long)row * ldc + col] = v;
        }
      }
    }
  }
}

// ---------------- row softmax, wave-per-row, register-resident ----------------
__global__ __launch_bounds__(256) void softmax_rows_kernel(f16* __restrict__ sc,
                                                           const int* __restrict__ lens) {
  const int tid = threadIdx.x;
  const int lane = tid & 63;
  const int row = blockIdx.x * 4 + (tid >> 6);
  const int len = lens[row >> 11];
  if ((row & 2047) >= ((len + 127) & ~127)) return;  // row never read downstream
  f16* p = sc + (long long)row * S_;

  f16x8 v[4];
#pragma unroll
  for (int c = 0; c < 4; ++c) v[c] = *(const f16x8*)(p + c * 512 + lane * 8);

  float m = -1e30f;
#pragma unroll
  for (int c = 0; c < 4; ++c)
#pragma unroll
    for (int j = 0; j < 8; ++j) {
      const int col = c * 512 + lane * 8 + j;
      if (col < len) m = fmaxf(m, (float)v[c][j]);
    }
#pragma unroll
  for (int o = 32; o > 0; o >>= 1) m = fmaxf(m, __shfl_xor(m, o, 64));

  float e[32];
  float s = 0.0f;
#pragma unroll
  for (int c = 0; c < 4; ++c)
#pragma unroll
    for (int j = 0; j < 8; ++j) {
      const int col = c * 512 + lane * 8 + j;
      const float x = (col < len) ? __expf((float)v[c][j] - m) : 0.0f;
      e[c * 8 + j] = x;
      s += x;
    }
#pragma unroll
  for (int o = 32; o > 0; o >>= 1) s += __shfl_xor(s, o, 64);
  const float inv = 1.0f / s;

#pragma unroll
  for (int c = 0; c < 4; ++c) {
    f16x8 w;
#pragma unroll
    for (int j = 0; j < 8; ++j) w[j] = (f16)(e[c * 8 + j] * inv);
    *(f16x8*)(p + c * 512 + lane * 8) = w;
  }
}

// ---------------- LayerNorm + ReLU + dot(W2) -> ts (fp32) and out_ts (fp32, masked)
__global__ __launch_bounds__(256) void ln_score_kernel(
    const float* __restrict__ h, const int* __restrict__ lens,
    const float* __restrict__ g, const float* __restrict__ bt,
    const float* __restrict__ W2, const float* __restrict__ b2,
    float* __restrict__ ts, float* __restrict__ out_ts) {
  const int token = blockIdx.x;
  const float* hp = h + (long long)token * D_;
  const int tid = threadIdx.x;
  float x0 = hp[tid], x1 = hp[tid + 256];
  __shared__ float r1[256], r2[256];
  r1[tid] = x0 + x1;
  r2[tid] = x0 * x0 + x1 * x1;
  __syncthreads();
  for (int o = 128; o > 0; o >>= 1) {
    if (tid < o) { r1[tid] += r1[tid + o]; r2[tid] += r2[tid + o]; }
    __syncthreads();
  }
  const float mu = r1[0] * (1.0f / D_);
  const float var = r2[0] * (1.0f / D_) - mu * mu;
  const float rs = rsqrtf(var + 1e-5f);
  float y0 = fmaxf((x0 - mu) * rs * g[tid] + bt[tid], 0.0f);
  float y1 = fmaxf((x1 - mu) * rs * g[tid + 256] + bt[tid + 256], 0.0f);
  float d = y0 * W2[tid] + y1 * W2[tid + 256];
  __syncthreads();
  r1[tid] = d;
  __syncthreads();
  for (int o = 128; o > 0; o >>= 1) {
    if (tid < o) r1[tid] += r1[tid + o];
    __syncthreads();
  }
  if (tid == 0) {
    float v = r1[0] + b2[0];
    ts[token] = v;
    const int b = token >> 11, s = token & (S_ - 1);
    out_ts[token] = (s < lens[b]) ? v : -10000.0f;
  }
}

// ---------------- rationale: cumsum + window argmax (ref tie-break) + span mask
__global__ __launch_bounds__(256) void rationale_kernel(
    const float* __restrict__ ts, const int* __restrict__ lens,
    float* __restrict__ out_rat, int* __restrict__ span) {
  const int b = blockIdx.x;
  const int tid = threadIdx.x;
  const int len = lens[b];
  __shared__ float cum[S_];
  __shared__ float rbest[256];
  __shared__ int ridx[256];

  for (int s = tid; s < S_; s += 256)
    cum[s] = (s < len) ? ts[b * S_ + s] : -10000.0f;
  __syncthreads();
  if (tid == 0) {  // sequential fp32 cumsum, matches np fp32 semantics
    float a = 0.0f;
    for (int s = 0; s < S_; ++s) { a += cum[s]; cum[s] = a; }
  }
  __syncthreads();

  float best = -3.4e38f;
  int bidx = 0x7fffffff;
  for (int idx = tid; idx < 18 * S_; idx += 256) {
    const int l = idx >> 11;
    const int s = idx & (S_ - 1);
    const int L = l + 3;
    if (L <= len && s <= len - L) {
      // NOTE: reference uses the PREFIX sum cum[s+L-1]/L (not the window sum)
      const float gv = cum[s + L - 1] / (float)L + 0.01f * ((float)L / 20.0f);
      if (gv > best) { best = gv; bidx = idx; }  // strict >: smallest idx within thread
    }
  }
  rbest[tid] = best;
  ridx[tid] = bidx;
  __syncthreads();
  for (int o = 128; o > 0; o >>= 1) {
    if (tid < o) {
      if (rbest[tid + o] > rbest[tid] ||
          (rbest[tid + o] == rbest[tid] && ridx[tid + o] < ridx[tid])) {
        rbest[tid] = rbest[tid + o];
        ridx[tid] = ridx[tid + o];
      }
    }
    __syncthreads();
  }
  const int bi = ridx[0];
  int start, sl;
  if (len <= 3) { start = 0; sl = len; }  // short-circuit case
  else { start = bi & (S_ - 1); sl = (bi >> 11) + 3; }
  if (tid == 0) { span[2 * b] = start; span[2 * b + 1] = sl; }
  for (int s = tid; s < S_; s += 256)
    out_rat[b * S_ + s] = (s >= start && s < start + sl) ? 1.0f : 0.0f;
}

// ---------------- token_probs: softmax over masked token scores (per batch) ----------------
__global__ __launch_bounds__(256) void tprobs_kernel(const float* __restrict__ ts,
                                                     const int* __restrict__ lens,
                                                     float* __restrict__ out) {
  const int b = blockIdx.x;
  const int tid = threadIdx.x;
  const int len = lens[b];
  const float* p = ts + b * S_;
  __shared__ float r[256];
  float m = -1e30f;
  for (int c = tid; c < len; c += 256) m = fmaxf(m, p[c]);
  r[tid] = m;
  __syncthreads();
  for (int o = 128; o > 0; o >>= 1) {
    if (tid < o) r[tid] = fmaxf(r[tid], r[tid + o]);
    __syncthreads();
  }
  m = r[0];
  __syncthreads();
  float s = 0.0f;
  for (int c = tid; c < len; c += 256) s += expf(p[c] - m);
  r[tid] = s;
  __syncthreads();
  for (int o = 128; o > 0; o >>= 1) {
    if (tid < o) r[tid] += r[tid + o];
    __syncthreads();
  }
  const float inv = 1.0f / r[0];
  for (int c = tid; c < S_; c += 256)
    out[b * S_ + c] = (c < len) ? expf(p[c] - m) * inv : 0.0f;
}

// ---------------- attended = hs * rationale (fp32 out) ----------------
__global__ __launch_bounds__(256) void attended_kernel(const float4* __restrict__ hs,
                                                       const int* __restrict__ span,
                                                       float4* __restrict__ out) {
  long long i = (long long)blockIdx.x * 256 + threadIdx.x;  // over B*S*H/4
  const int token = (int)(i >> 8);  // / (H_/4)
  const int b = token >> 11;
  const int s = token & (S_ - 1);
  const int st = span[2 * b], ln = span[2 * b + 1];
  float4 v = {0.0f, 0.0f, 0.0f, 0.0f};
  if (s >= st && s < st + ln) v = hs[i];
  out[i] = v;
}

// ---------------- pooled = sum over span / (len + 1e-6) (fp32 out) ----------------
__global__ __launch_bounds__(256) void pooled_kernel(const float* __restrict__ hs,
                                                     const int* __restrict__ span,
                                                     float* __restrict__ out) {
  const int b = blockIdx.x;
  const int tid = threadIdx.x;
  const int st = span[2 * b], ln = span[2 * b + 1];
  const float inv = 1.0f / ((float)ln + 1e-6f);
  for (int h = tid; h < H_; h += 256) {
    float s = 0.0f;
    for (int t = st; t < st + ln; ++t)
      s += hs[(long long)(b * S_ + t) * H_ + h];
    out[b * H_ + h] = s * inv;
  }
}

// ---------------- launch ----------------
extern "C" void kernel_launch(void* const* d_in, const int* in_sizes, int n_in,
                              void* d_out, int out_size, void* d_ws, size_t ws_size,
                              hipStream_t stream) {
  const float* hs = (const float*)d_in[0];
  const int* amask = (const int*)d_in[1];
  const float* Wq = (const float*)d_in[2];
  const float* bq = (const float*)d_in[3];
  const float* Wk = (const float*)d_in[4];
  const float* bk = (const float*)d_in[5];
  const float* W1 = (const float*)d_in[6];
  const float* b1 = (const float*)d_in[7];
  const float* ln_g = (const float*)d_in[8];
  const float* ln_b = (const float*)d_in[9];
  const float* W2 = (const float*)d_in[10];
  const float* b2 = (const float*)d_in[11];

  float* out = (float*)d_out;  // reference outputs are float32
  char* ws = (char*)d_ws;

  // workspace layout (bytes)
  const long long off_hs16 = 0;           // 67,108,864  (fp16 hs; later reused as fp32 h)
  const long long off_qk = 67108864;      // 67,108,864  (32768 x 1024 fp16: [Q|K])
  const long long off_vt = 134217728;     // 33,554,432  (vt[b][d][t] fp16)
  const long long off_wt = 167772160;     // 3,145,728
  const long long off_bias = 170917888;   // 8,192
  const long long off_ts = 170926080;     // 131,072
  const long long off_lens = 171057152;   // 64
  const long long off_span = 171057216;   // 192
  const long long off_scores = 171057408; // nb * 8,388,608

  f16* hs16 = (f16*)(ws + off_hs16);
  float* hbuf = (float*)(ws + off_hs16);  // alias: hs16 dead after QK/V GEMMs
  f16* qk16 = (f16*)(ws + off_qk);
  f16* vt = (f16*)(ws + off_vt);
  f16* Wt = (f16*)(ws + off_wt);
  float* bias_qk = (float*)(ws + off_bias);
  float* ts = (float*)(ws + off_ts);
  int* lens = (int*)(ws + off_lens);
  int* span = (int*)(ws + off_span);
  f16* scores = (f16*)(ws + off_scores);

  // adaptive batch-chunking of the scores buffer to fit ws_size
  const long long SC_PER_B = (long long)S_ * S_ * 2;  // 8,388,608 B
  int nb = 16;
  while (nb > 1 && off_scores + (long long)nb * SC_PER_B > (long long)ws_size) nb >>= 1;

  // output sections (fp32 elements)
  float* out_ts = out;                  // 16*2048
  float* out_rat = out + 32768;         // 16*2048
  float* out_tp = out + 65536;          // 16*2048
  float4* out_att = (float4*)(out + 98304);  // 16*2048*1024
  float* out_pool = out + 33652736;     // 16*1024

  hipLaunchKernelGGL(lens_kernel, dim3(B_), dim3(256), 0, stream, amask, lens);
  hipLaunchKernelGGL(cvt_hs_kernel, dim3(32768), dim3(256), 0, stream,
                     (const float4*)hs, (f16x4v*)hs16);
  hipLaunchKernelGGL(build_wt_kernel, dim3(6144), dim3(256), 0, stream, Wq, Wk, W1, Wt);
  hipLaunchKernelGGL(build_bias_kernel, dim3(4), dim3(256), 0, stream, bq, bk, bias_qk);

  // QK: (32768 x 1024) = hs16 @ Wt[0:1024]^T  (+[bq|bk]); skip token blocks >= len
  hipLaunchKernelGGL(gemm_bt, dim3(8, 256, 1), dim3(256), 0, stream,
                     hs16, Wt, (void*)qk16, 1024, 1024, 1024, 1024,
                     0LL, 0LL, 0LL, 1.0f, bias_qk, 1, lens, 1);
  // V: (32768 x 512) = hs16 @ Wt[1024:1536]^T + b1, stored transposed into vt[b][d][t]
  hipLaunchKernelGGL(gemm_bt, dim3(4, 256, 1), dim3(256), 0, stream,
                     hs16, Wt + 1024 * 1024, (void*)vt, 1024, 1024, 1024, 2048,
                     0LL, 0LL, 0LL, 1.0f, b1, 2, lens, 1);

  const int chunks = 16 / nb;
  for (int c = 0; c < chunks; ++c) {
    const int b0 = c * nb;
    // scores: per batch (2048x2048) = Q @ K^T / sqrt(512), fp16; skip dead m/n blocks
    hipLaunchKernelGGL(gemm_bt, dim3(16, 16, nb), dim3(256), 0, stream,
                       qk16 + (long long)b0 * S_ * 1024,
                       qk16 + (long long)b0 * S_ * 1024 + 512,
                       (void*)scores, 512, 1024, 1024, 2048,
                       (long long)S_ * 1024, (long long)S_ * 1024, (long long)S_ * S_,
                       0.044194173824159216f /* 1/sqrt(512) */, (const float*)nullptr, 1,
                       lens + b0, 2 | 4);
    hipLaunchKernelGGL(softmax_rows_kernel, dim3(nb * S_ / 4), dim3(256), 0, stream,
                       scores, lens + b0);
    // h: per batch (2048x512) = P @ V (b1 folded into V; P rows sum to 1);
    // skip dead row blocks, clamp K to ceil64(len) (P is exactly 0 beyond len)
    hipLaunchKernelGGL(gemm_bt, dim3(4, 16, nb), dim3(256), 0, stream,
                       scores, vt + ((long long)b0 << 20),
                       (void*)(hbuf + (long long)b0 * S_ * D_), 2048, 2048, 2048, 512,
                       (long long)S_ * S_, 1LL << 20, (long long)S_ * D_,
                       1.0f, (const float*)nullptr, 0, lens + b0, 2 | 8);
  }

  hipLaunchKernelGGL(ln_score_kernel, dim3(B_ * S_), dim3(256), 0, stream,
                     hbuf, lens, ln_g, ln_b, W2, b2, ts, out_ts);

  hipLaunchKernelGGL(rationale_kernel, dim3(B_), dim3(256), 0, stream,
                     ts, lens, out_rat, span);
  hipLaunchKernelGGL(tprobs_kernel, dim3(B_), dim3(256), 0, stream, ts, lens, out_tp);
  hipLaunchKernelGGL(attended_kernel, dim3(32768), dim3(256), 0, stream,
                     (const float4*)hs, span, out_att);
  hipLaunchKernelGGL(pooled_kernel, dim3(B_), dim3(256), 0, stream, hs, span, out_pool);
}

// Round 4
// 729.250 us; speedup vs baseline: 1.2383x; 1.0353x over previous
//
#include <hip/hip_runtime.h>

typedef _Float16 f16;
typedef __attribute__((ext_vector_type(8))) _Float16 f16x8;
typedef __attribute__((ext_vector_type(4))) _Float16 f16x4v;
typedef __attribute__((ext_vector_type(4))) float f32x4;

#define B_ 16
#define S_ 2048
#define H_ 1024
#define D_ 512

// async 16B global->LDS; lds dest is wave-uniform base + lane*16
__device__ __forceinline__ void gload16(const f16* g, f16* l) {
  __builtin_amdgcn_global_load_lds(
      (const __attribute__((address_space(1))) unsigned int*)g,
      (__attribute__((address_space(3))) unsigned int*)l, 16, 0, 0);
}

// ---------------- fp32 -> fp16 convert (hidden states) ----------------
__global__ __launch_bounds__(256) void cvt_hs_kernel(const float4* __restrict__ in,
                                                     f16x4v* __restrict__ out) {
  long long i = (long long)blockIdx.x * 256 + threadIdx.x;  // 8,388,608 total
  float4 v = in[i];
  f16x4v o = {(f16)v.x, (f16)v.y, (f16)v.z, (f16)v.w};
  out[i] = o;
}

// ---------------- Wt (1536 x 1024) fp16: rows 0-511 Wq^T, 512-1023 Wk^T, 1024-1535 W1^T
__global__ __launch_bounds__(256) void build_wt_kernel(const float* __restrict__ Wq,
                                                       const float* __restrict__ Wk,
                                                       const float* __restrict__ W1,
                                                       f16* __restrict__ Wt) {
  int i = blockIdx.x * 256 + threadIdx.x;  // 1536*1024
  int n = i >> 10;
  int k = i & 1023;
  const float* src = (n < 512) ? Wq : ((n < 1024) ? Wk : W1);
  int nn = n & 511;
  Wt[i] = (f16)src[k * 512 + nn];
}

__global__ __launch_bounds__(256) void build_bias_kernel(const float* __restrict__ bq,
                                                         const float* __restrict__ bk,
                                                         float* __restrict__ bias) {
  int i = blockIdx.x * 256 + threadIdx.x;
  if (i < 1024) bias[i] = (i < 512) ? bq[i] : bk[i - 512];
}

// ---------------- per-batch valid length ----------------
__global__ __launch_bounds__(256) void lens_kernel(const int* __restrict__ mask,
                                                   int* __restrict__ lens) {
  int b = blockIdx.x;
  int tid = threadIdx.x;
  int s = 0;
  for (int c = tid; c < S_; c += 256) s += mask[b * S_ + c];
  __shared__ int r[256];
  r[tid] = s;
  __syncthreads();
  for (int o = 128; o > 0; o >>= 1) {
    if (tid < o) r[tid] += r[tid + o];
    __syncthreads();
  }
  if (tid == 0) lens[b] = r[0];
}

// ---------------- GEMM: C[m][n] = scale * (sum_k A[m][k]*Bt[n][k]) + bias[n]
// 128x128 tile, BK=64, mfma_f32_16x16x32_f16, async global_load_lds staging,
// XOR-swizzled LDS (col-group ^ (row&7)): zero bank conflicts (verified R3).
// Dispatch-order swizzle: groups of 8 m-tiles x all n-tiles are temporally
// adjacent so A-tiles are L2/L3-resident across their n-sweep (kills the 4x
// HBM refetch seen in R3: FETCH 204MB on QK).
// mode: 0=f32 store, 1=f16 store, 2=f16 store transposed into vt[b][d][t].
// lflags: 1 = len from lens[m0>>11], skip block if (m0&2047) >= len  (QKV gemms)
//         2 = len from lens[bz], skip if (m0&2047) >= len            (scores/PV)
//         4 = skip if n0 >= len                                      (scores)
//         8 = clamp K to ceil64(len)                                 (PV)
__global__ __launch_bounds__(256) void gemm_bt(
    const f16* __restrict__ A, const f16* __restrict__ Bm, void* __restrict__ Cout,
    int K, int lda, int ldb, int ldc,
    long long sA, long long sB, long long sC,
    float scale, const float* __restrict__ bias, int mode,
    const int* __restrict__ lens, int lflags) {
  const int bz = blockIdx.z;

  // ---- block swizzle: A-tile-group-major dispatch order (bijective remap)
  const int ntiles = gridDim.x, mtiles = gridDim.y;
  const int flat = blockIdx.y * ntiles + blockIdx.x;
  const int per = 8 * ntiles;
  const int grp = flat / per;
  const int rem = flat - grp * per;
  const int gbase = grp * 8;
  const int gsz = (mtiles - gbase) < 8 ? (mtiles - gbase) : 8;
  const int mt = gbase + rem % gsz;
  const int nt = rem / gsz;
  const int m0 = mt * 128;
  const int n0 = nt * 128;

  int Keff = K;
  if (lflags) {
    const int len = lens[(lflags & 1) ? (m0 >> 11) : bz];
    if ((lflags & 3) && (m0 & 2047) >= len) return;
    if ((lflags & 4) && n0 >= len) return;
    if (lflags & 8) { int kl = (len + 63) & ~63; Keff = kl < K ? kl : K; }
  }

  A += (long long)bz * sA;
  Bm += (long long)bz * sB;

  __shared__ f16 As[128 * 64];
  __shared__ f16 Bs[128 * 64];

  const int tid = threadIdx.x;
  const int lane = tid & 63;
  const int wid = tid >> 6;
  const int wm = wid & 1, wn = wid >> 1;

  f32x4 acc[4][4] = {};

  const int lr8 = lane >> 3;  // row within 8-row staging group
  const int sg = lane & 7;    // LDS slot col-group

  for (int k0 = 0; k0 < Keff; k0 += 64) {
#pragma unroll
    for (int it = 0; it < 4; ++it) {
      const int r0 = it * 32 + wid * 8;
      const int r = r0 + lr8;
      const int cg = sg ^ (r & 7);  // source col-group for swizzled slot
      gload16(A + (long long)(m0 + r) * lda + k0 + cg * 8, As + r0 * 64);
      gload16(Bm + (long long)(n0 + r) * ldb + k0 + cg * 8, Bs + r0 * 64);
    }
    __syncthreads();

#pragma unroll
    for (int kk = 0; kk < 64; kk += 32) {
      const int cg = (kk >> 3) + (lane >> 4);
      f16x8 af[4], bf[4];
#pragma unroll
      for (int i = 0; i < 4; ++i) {
        const int row = wm * 64 + i * 16 + (lane & 15);
        af[i] = *(const f16x8*)(As + row * 64 + ((cg ^ (row & 7)) << 3));
      }
#pragma unroll
      for (int j = 0; j < 4; ++j) {
        const int row = wn * 64 + j * 16 + (lane & 15);
        bf[j] = *(const f16x8*)(Bs + row * 64 + ((cg ^ (row & 7)) << 3));
      }
#pragma unroll
      for (int i = 0; i < 4; ++i)
#pragma unroll
        for (int j = 0; j < 4; ++j)
          acc[i][j] = __builtin_amdgcn_mfma_f32_16x16x32_f16(af[i], bf[j], acc[i][j], 0, 0, 0);
    }
    __syncthreads();
  }

  const long long cb = (long long)bz * sC;
  const int lr = ((lane >> 4) << 2);
  const int lc = lane & 15;
#pragma unroll
  for (int i = 0; i < 4; ++i) {
#pragma unroll
    for (int j = 0; j < 4; ++j) {
      const int col = n0 + wn * 64 + j * 16 + lc;
      const float bv = bias ? bias[col] : 0.0f;
      if (mode == 2) {
        const int rowb = m0 + wm * 64 + i * 16 + lr;  // 4 consecutive tokens
        const int b = rowb >> 11, t = rowb & 2047;
        f16x4v pk;
#pragma unroll
        for (int r = 0; r < 4; ++r) pk[r] = (f16)(acc[i][j][r] * scale + bv);
        *(f16x4v*)((f16*)Cout + ((long long)b << 20) + (long long)col * 2048 + t) = pk;
      } else {
#pragma unroll
        for (int r = 0; r < 4; ++r) {
          const int row = m0 + wm * 64 + i * 16 + lr + r;
          float v = acc[i][j][r] * scale + bv;
          if (mode == 1)
            ((f16*)Cout)[cb + (long long)row * ldc + col] = (f16)v;
          else
            ((float*)Cout)[cb + (long long)row * ldc + col] = v;
        }
      }
    }
  }
}

// ---------------- row softmax, wave-per-row, register-resident ----------------
__global__ __launch_bounds__(256) void softmax_rows_kernel(f16* __restrict__ sc,
                                                           const int* __restrict__ lens) {
  const int tid = threadIdx.x;
  const int lane = tid & 63;
  const int row = blockIdx.x * 4 + (tid >> 6);
  const int len = lens[row >> 11];
  if ((row & 2047) >= ((len + 127) & ~127)) return;  // row never read downstream
  f16* p = sc + (long long)row * S_;

  f16x8 v[4];
#pragma unroll
  for (int c = 0; c < 4; ++c) v[c] = *(const f16x8*)(p + c * 512 + lane * 8);

  float m = -1e30f;
#pragma unroll
  for (int c = 0; c < 4; ++c)
#pragma unroll
    for (int j = 0; j < 8; ++j) {
      const int col = c * 512 + lane * 8 + j;
      if (col < len) m = fmaxf(m, (float)v[c][j]);
    }
#pragma unroll
  for (int o = 32; o > 0; o >>= 1) m = fmaxf(m, __shfl_xor(m, o, 64));

  float e[32];
  float s = 0.0f;
#pragma unroll
  for (int c = 0; c < 4; ++c)
#pragma unroll
    for (int j = 0; j < 8; ++j) {
      const int col = c * 512 + lane * 8 + j;
      const float x = (col < len) ? __expf((float)v[c][j] - m) : 0.0f;
      e[c * 8 + j] = x;
      s += x;
    }
#pragma unroll
  for (int o = 32; o > 0; o >>= 1) s += __shfl_xor(s, o, 64);
  const float inv = 1.0f / s;

#pragma unroll
  for (int c = 0; c < 4; ++c) {
    f16x8 w;
#pragma unroll
    for (int j = 0; j < 8; ++j) w[j] = (f16)(e[c * 8 + j] * inv);
    *(f16x8*)(p + c * 512 + lane * 8) = w;
  }
}

// ---------------- LayerNorm + ReLU + dot(W2) -> ts (fp32) and out_ts (fp32, masked)
__global__ __launch_bounds__(256) void ln_score_kernel(
    const float* __restrict__ h, const int* __restrict__ lens,
    const float* __restrict__ g, const float* __restrict__ bt,
    const float* __restrict__ W2, const float* __restrict__ b2,
    float* __restrict__ ts, float* __restrict__ out_ts) {
  const int token = blockIdx.x;
  const float* hp = h + (long long)token * D_;
  const int tid = threadIdx.x;
  float x0 = hp[tid], x1 = hp[tid + 256];
  __shared__ float r1[256], r2[256];
  r1[tid] = x0 + x1;
  r2[tid] = x0 * x0 + x1 * x1;
  __syncthreads();
  for (int o = 128; o > 0; o >>= 1) {
    if (tid < o) { r1[tid] += r1[tid + o]; r2[tid] += r2[tid + o]; }
    __syncthreads();
  }
  const float mu = r1[0] * (1.0f / D_);
  const float var = r2[0] * (1.0f / D_) - mu * mu;
  const float rs = rsqrtf(var + 1e-5f);
  float y0 = fmaxf((x0 - mu) * rs * g[tid] + bt[tid], 0.0f);
  float y1 = fmaxf((x1 - mu) * rs * g[tid + 256] + bt[tid + 256], 0.0f);
  float d = y0 * W2[tid] + y1 * W2[tid + 256];
  __syncthreads();
  r1[tid] = d;
  __syncthreads();
  for (int o = 128; o > 0; o >>= 1) {
    if (tid < o) r1[tid] += r1[tid + o];
    __syncthreads();
  }
  if (tid == 0) {
    float v = r1[0] + b2[0];
    ts[token] = v;
    const int b = token >> 11, s = token & (S_ - 1);
    out_ts[token] = (s < lens[b]) ? v : -10000.0f;
  }
}

// ---------------- rationale: cumsum + window argmax (ref tie-break) + span mask
__global__ __launch_bounds__(256) void rationale_kernel(
    const float* __restrict__ ts, const int* __restrict__ lens,
    float* __restrict__ out_rat, int* __restrict__ span) {
  const int b = blockIdx.x;
  const int tid = threadIdx.x;
  const int len = lens[b];
  __shared__ float cum[S_];
  __shared__ float rbest[256];
  __shared__ int ridx[256];

  for (int s = tid; s < S_; s += 256)
    cum[s] = (s < len) ? ts[b * S_ + s] : -10000.0f;
  __syncthreads();
  if (tid == 0) {
    // sequential fp32 cumsum (exact np order) in registers: the dependent
    // chain is 4-cyc fp adds, not LDS round-trips (R3 version: ~2048 LDS RTs)
    float a = 0.0f;
    for (int s = 0; s < S_; s += 4) {
      float4 v = *(float4*)(cum + s);
      a += v.x; v.x = a;
      a += v.y; v.y = a;
      a += v.z; v.z = a;
      a += v.w; v.w = a;
      *(float4*)(cum + s) = v;
    }
  }
  __syncthreads();

  float best = -3.4e38f;
  int bidx = 0x7fffffff;
  for (int idx = tid; idx < 18 * S_; idx += 256) {
    const int l = idx >> 11;
    const int s = idx & (S_ - 1);
    const int L = l + 3;
    if (L <= len && s <= len - L) {
      // NOTE: reference uses the PREFIX sum cum[s+L-1]/L (not the window sum)
      const float gv = cum[s + L - 1] / (float)L + 0.01f * ((float)L / 20.0f);
      if (gv > best) { best = gv; bidx = idx; }  // strict >: smallest idx within thread
    }
  }
  rbest[tid] = best;
  ridx[tid] = bidx;
  __syncthreads();
  for (int o = 128; o > 0; o >>= 1) {
    if (tid < o) {
      if (rbest[tid + o] > rbest[tid] ||
          (rbest[tid + o] == rbest[tid] && ridx[tid + o] < ridx[tid])) {
        rbest[tid] = rbest[tid + o];
        ridx[tid] = ridx[tid + o];
      }
    }
    __syncthreads();
  }
  const int bi = ridx[0];
  int start, sl;
  if (len <= 3) { start = 0; sl = len; }  // short-circuit case
  else { start = bi & (S_ - 1); sl = (bi >> 11) + 3; }
  if (tid == 0) { span[2 * b] = start; span[2 * b + 1] = sl; }
  for (int s = tid; s < S_; s += 256)
    out_rat[b * S_ + s] = (s >= start && s < start + sl) ? 1.0f : 0.0f;
}

// ---------------- token_probs: softmax over masked token scores (per batch) ----------------
__global__ __launch_bounds__(256) void tprobs_kernel(const float* __restrict__ ts,
                                                     const int* __restrict__ lens,
                                                     float* __restrict__ out) {
  const int b = blockIdx.x;
  const int tid = threadIdx.x;
  const int len = lens[b];
  const float* p = ts + b * S_;
  __shared__ float r[256];
  float m = -1e30f;
  for (int c = tid; c < len; c += 256) m = fmaxf(m, p[c]);
  r[tid] = m;
  __syncthreads();
  for (int o = 128; o > 0; o >>= 1) {
    if (tid < o) r[tid] = fmaxf(r[tid], r[tid + o]);
    __syncthreads();
  }
  m = r[0];
  __syncthreads();
  float s = 0.0f;
  for (int c = tid; c < len; c += 256) s += expf(p[c] - m);
  r[tid] = s;
  __syncthreads();
  for (int o = 128; o > 0; o >>= 1) {
    if (tid < o) r[tid] += r[tid + o];
    __syncthreads();
  }
  const float inv = 1.0f / r[0];
  for (int c = tid; c < S_; c += 256)
    out[b * S_ + c] = (c < len) ? expf(p[c] - m) * inv : 0.0f;
}

// ---------------- attended = hs * rationale (fp32 out) ----------------
__global__ __launch_bounds__(256) void attended_kernel(const float4* __restrict__ hs,
                                                       const int* __restrict__ span,
                                                       float4* __restrict__ out) {
  long long i = (long long)blockIdx.x * 256 + threadIdx.x;  // over B*S*H/4
  const int token = (int)(i >> 8);  // / (H_/4)
  const int b = token >> 11;
  const int s = token & (S_ - 1);
  const int st = span[2 * b], ln = span[2 * b + 1];
  float4 v = {0.0f, 0.0f, 0.0f, 0.0f};
  if (s >= st && s < st + ln) v = hs[i];
  out[i] = v;
}

// ---------------- pooled = sum over span / (len + 1e-6) (fp32 out) ----------------
__global__ __launch_bounds__(256) void pooled_kernel(const float* __restrict__ hs,
                                                     const int* __restrict__ span,
                                                     float* __restrict__ out) {
  const int b = blockIdx.x;
  const int tid = threadIdx.x;
  const int st = span[2 * b], ln = span[2 * b + 1];
  const float inv = 1.0f / ((float)ln + 1e-6f);
  for (int h = tid; h < H_; h += 256) {
    float s = 0.0f;
    for (int t = st; t < st + ln; ++t)
      s += hs[(long long)(b * S_ + t) * H_ + h];
    out[b * H_ + h] = s * inv;
  }
}

// ---------------- launch ----------------
extern "C" void kernel_launch(void* const* d_in, const int* in_sizes, int n_in,
                              void* d_out, int out_size, void* d_ws, size_t ws_size,
                              hipStream_t stream) {
  const float* hs = (const float*)d_in[0];
  const int* amask = (const int*)d_in[1];
  const float* Wq = (const float*)d_in[2];
  const float* bq = (const float*)d_in[3];
  const float* Wk = (const float*)d_in[4];
  const float* bk = (const float*)d_in[5];
  const float* W1 = (const float*)d_in[6];
  const float* b1 = (const float*)d_in[7];
  const float* ln_g = (const float*)d_in[8];
  const float* ln_b = (const float*)d_in[9];
  const float* W2 = (const float*)d_in[10];
  const float* b2 = (const float*)d_in[11];

  float* out = (float*)d_out;  // reference outputs are float32
  char* ws = (char*)d_ws;

  // workspace layout (bytes)
  const long long off_hs16 = 0;           // 67,108,864  (fp16 hs; later reused as fp32 h)
  const long long off_qk = 67108864;      // 67,108,864  (32768 x 1024 fp16: [Q|K])
  const long long off_vt = 134217728;     // 33,554,432  (vt[b][d][t] fp16)
  const long long off_wt = 167772160;     // 3,145,728
  const long long off_bias = 170917888;   // 8,192
  const long long off_ts = 170926080;     // 131,072
  const long long off_lens = 171057152;   // 64
  const long long off_span = 171057216;   // 192
  const long long off_scores = 171057408; // nb * 8,388,608

  f16* hs16 = (f16*)(ws + off_hs16);
  float* hbuf = (float*)(ws + off_hs16);  // alias: hs16 dead after QK/V GEMMs
  f16* qk16 = (f16*)(ws + off_qk);
  f16* vt = (f16*)(ws + off_vt);
  f16* Wt = (f16*)(ws + off_wt);
  float* bias_qk = (float*)(ws + off_bias);
  float* ts = (float*)(ws + off_ts);
  int* lens = (int*)(ws + off_lens);
  int* span = (int*)(ws + off_span);
  f16* scores = (f16*)(ws + off_scores);

  // adaptive batch-chunking of the scores buffer to fit ws_size
  const long long SC_PER_B = (long long)S_ * S_ * 2;  // 8,388,608 B
  int nb = 16;
  while (nb > 1 && off_scores + (long long)nb * SC_PER_B > (long long)ws_size) nb >>= 1;

  // output sections (fp32 elements)
  float* out_ts = out;                  // 16*2048
  float* out_rat = out + 32768;         // 16*2048
  float* out_tp = out + 65536;          // 16*2048
  float4* out_att = (float4*)(out + 98304);  // 16*2048*1024
  float* out_pool = out + 33652736;     // 16*1024

  hipLaunchKernelGGL(lens_kernel, dim3(B_), dim3(256), 0, stream, amask, lens);
  hipLaunchKernelGGL(cvt_hs_kernel, dim3(32768), dim3(256), 0, stream,
                     (const float4*)hs, (f16x4v*)hs16);
  hipLaunchKernelGGL(build_wt_kernel, dim3(6144), dim3(256), 0, stream, Wq, Wk, W1, Wt);
  hipLaunchKernelGGL(build_bias_kernel, dim3(4), dim3(256), 0, stream, bq, bk, bias_qk);

  // QK: (32768 x 1024) = hs16 @ Wt[0:1024]^T  (+[bq|bk]); skip token blocks >= len
  hipLaunchKernelGGL(gemm_bt, dim3(8, 256, 1), dim3(256), 0, stream,
                     hs16, Wt, (void*)qk16, 1024, 1024, 1024, 1024,
                     0LL, 0LL, 0LL, 1.0f, bias_qk, 1, lens, 1);
  // V: (32768 x 512) = hs16 @ Wt[1024:1536]^T + b1, stored transposed into vt[b][d][t]
  hipLaunchKernelGGL(gemm_bt, dim3(4, 256, 1), dim3(256), 0, stream,
                     hs16, Wt + 1024 * 1024, (void*)vt, 1024, 1024, 1024, 2048,
                     0LL, 0LL, 0LL, 1.0f, b1, 2, lens, 1);

  const int chunks = 16 / nb;
  for (int c = 0; c < chunks; ++c) {
    const int b0 = c * nb;
    // scores: per batch (2048x2048) = Q @ K^T / sqrt(512), fp16; skip dead m/n blocks
    hipLaunchKernelGGL(gemm_bt, dim3(16, 16, nb), dim3(256), 0, stream,
                       qk16 + (long long)b0 * S_ * 1024,
                       qk16 + (long long)b0 * S_ * 1024 + 512,
                       (void*)scores, 512, 1024, 1024, 2048,
                       (long long)S_ * 1024, (long long)S_ * 1024, (long long)S_ * S_,
                       0.044194173824159216f /* 1/sqrt(512) */, (const float*)nullptr, 1,
                       lens + b0, 2 | 4);
    hipLaunchKernelGGL(softmax_rows_kernel, dim3(nb * S_ / 4), dim3(256), 0, stream,
                       scores, lens + b0);
    // h: per batch (2048x512) = P @ V (b1 folded into V; P rows sum to 1);
    // skip dead row blocks, clamp K to ceil64(len) (P is exactly 0 beyond len)
    hipLaunchKernelGGL(gemm_bt, dim3(4, 16, nb), dim3(256), 0, stream,
                       scores, vt + ((long long)b0 << 20),
                       (void*)(hbuf + (long long)b0 * S_ * D_), 2048, 2048, 2048, 512,
                       (long long)S_ * S_, 1LL << 20, (long long)S_ * D_,
                       1.0f, (const float*)nullptr, 0, lens + b0, 2 | 8);
  }

  hipLaunchKernelGGL(ln_score_kernel, dim3(B_ * S_), dim3(256), 0, stream,
                     hbuf, lens, ln_g, ln_b, W2, b2, ts, out_ts);

  hipLaunchKernelGGL(rationale_kernel, dim3(B_), dim3(256), 0, stream,
                     ts, lens, out_rat, span);
  hipLaunchKernelGGL(tprobs_kernel, dim3(B_), dim3(256), 0, stream, ts, lens, out_tp);
  hipLaunchKernelGGL(attended_kernel, dim3(32768), dim3(256), 0, stream,
                     (const float4*)hs, span, out_att);
  hipLaunchKernelGGL(pooled_kernel, dim3(B_), dim3(256), 0, stream, hs, span, out_pool);
}

// Round 5
// 667.594 us; speedup vs baseline: 1.3526x; 1.0924x over previous
//
#include <hip/hip_runtime.h>

typedef _Float16 f16;
typedef __attribute__((ext_vector_type(8))) _Float16 f16x8;
typedef __attribute__((ext_vector_type(4))) _Float16 f16x4v;
typedef __attribute__((ext_vector_type(4))) float f32x4;

#define B_ 16
#define S_ 2048
#define H_ 1024
#define D_ 512

// async 16B global->LDS; lds dest is wave-uniform base + lane*16
__device__ __forceinline__ void gload16(const f16* g, f16* l) {
  __builtin_amdgcn_global_load_lds(
      (const __attribute__((address_space(1))) unsigned int*)g,
      (__attribute__((address_space(3))) unsigned int*)l, 16, 0, 0);
}

// ---------------- fp32 -> fp16 convert (hidden states) ----------------
__global__ __launch_bounds__(256) void cvt_hs_kernel(const float4* __restrict__ in,
                                                     f16x4v* __restrict__ out) {
  long long i = (long long)blockIdx.x * 256 + threadIdx.x;  // 8,388,608 total
  float4 v = in[i];
  f16x4v o = {(f16)v.x, (f16)v.y, (f16)v.z, (f16)v.w};
  out[i] = o;
}

// ---------------- fused setup: Wt (1536x1024 f16), bias_full[1536], lens[16]
__global__ __launch_bounds__(256) void setup_kernel(
    const float* __restrict__ Wq, const float* __restrict__ Wk,
    const float* __restrict__ W1, const float* __restrict__ bq,
    const float* __restrict__ bk, const float* __restrict__ b1,
    const int* __restrict__ mask, f16* __restrict__ Wt,
    float* __restrict__ bias, int* __restrict__ lens) {
  const int blk = blockIdx.x;
  const int tid = threadIdx.x;
  if (blk < 6144) {
    int i = blk * 256 + tid;
    int n = i >> 10;
    int k = i & 1023;
    const float* src = (n < 512) ? Wq : ((n < 1024) ? Wk : W1);
    Wt[i] = (f16)src[k * 512 + (n & 511)];
  } else if (blk < 6150) {
    int i = (blk - 6144) * 256 + tid;
    if (i < 1536) bias[i] = (i < 512) ? bq[i] : ((i < 1024) ? bk[i - 512] : b1[i - 1024]);
  } else {
    int b = blk - 6150;  // 0..15
    int s = 0;
    for (int c = tid; c < S_; c += 256) s += mask[b * S_ + c];
    __shared__ int r[256];
    r[tid] = s;
    __syncthreads();
    for (int o = 128; o > 0; o >>= 1) {
      if (tid < o) r[tid] += r[tid + o];
      __syncthreads();
    }
    if (tid == 0) lens[b] = r[0];
  }
}

// ---------------- GEMM: C[m][n] = scale * (sum_k A[m][k]*Bt[n][k]) + bias[n]
// 128x128 tile, BK=64, mfma_f32_16x16x32_f16, async global_load_lds staging,
// XOR-swizzled LDS (zero bank conflicts, verified R3), mgrp-sized m-tile-group
// dispatch order for A-tile L2 residency (verified R4: FETCH 204->126MB).
// MW template arg = min waves/SIMD (4 => <=128 regs/wave => 4 blocks/CU).
// mode: 0=f32 store, 1=f16 store, 2=f16 transposed store into vt[b][d][t],
//       3=fused QKV: col<1024 -> Cout (qk16, ldc), col>=1024 -> Cout2 (vt, transposed)
// lflags: 1 = len from lens[m0>>11], skip block if (m0&2047) >= len  (QKV)
//         2 = len from lens[bz], skip if (m0&2047) >= len            (scores/PV)
//         4 = skip if n0 >= len                                      (scores)
//         8 = clamp K to ceil64(len)                                 (PV)
template <int MW>
__global__ __launch_bounds__(256, MW) void gemm_bt(
    const f16* __restrict__ A, const f16* __restrict__ Bm, void* __restrict__ Cout,
    void* __restrict__ Cout2,
    int K, int lda, int ldb, int ldc,
    long long sA, long long sB, long long sC,
    float scale, const float* __restrict__ bias, int mode,
    const int* __restrict__ lens, int lflags, int mgrp) {
  const int bz = blockIdx.z;

  // ---- block swizzle: A-tile-group-major dispatch order (bijective remap)
  const int ntiles = gridDim.x, mtiles = gridDim.y;
  const int flat = blockIdx.y * ntiles + blockIdx.x;
  const int per = mgrp * ntiles;
  const int grp = flat / per;
  const int rem = flat - grp * per;
  const int gbase = grp * mgrp;
  int gsz = mtiles - gbase;
  if (gsz > mgrp) gsz = mgrp;
  const int mt = gbase + rem % gsz;
  const int nt = rem / gsz;
  const int m0 = mt * 128;
  const int n0 = nt * 128;

  int Keff = K;
  if (lflags) {
    const int len = lens[(lflags & 1) ? (m0 >> 11) : bz];
    if ((lflags & 3) && (m0 & 2047) >= len) return;
    if ((lflags & 4) && n0 >= len) return;
    if (lflags & 8) { int kl = (len + 63) & ~63; Keff = kl < K ? kl : K; }
  }

  A += (long long)bz * sA;
  Bm += (long long)bz * sB;

  __shared__ f16 As[128 * 64];
  __shared__ f16 Bs[128 * 64];

  const int tid = threadIdx.x;
  const int lane = tid & 63;
  const int wid = tid >> 6;
  const int wm = wid & 1, wn = wid >> 1;

  f32x4 acc[4][4] = {};

  const int lr8 = lane >> 3;  // row within 8-row staging group
  const int sg = lane & 7;    // LDS slot col-group

  for (int k0 = 0; k0 < Keff; k0 += 64) {
#pragma unroll
    for (int it = 0; it < 4; ++it) {
      const int r0 = it * 32 + wid * 8;
      const int r = r0 + lr8;
      const int cg = sg ^ (r & 7);  // source col-group for swizzled slot
      gload16(A + (long long)(m0 + r) * lda + k0 + cg * 8, As + r0 * 64);
      gload16(Bm + (long long)(n0 + r) * ldb + k0 + cg * 8, Bs + r0 * 64);
    }
    __syncthreads();

#pragma unroll
    for (int kk = 0; kk < 64; kk += 32) {
      const int cg = (kk >> 3) + (lane >> 4);
      f16x8 af[4], bf[4];
#pragma unroll
      for (int i = 0; i < 4; ++i) {
        const int row = wm * 64 + i * 16 + (lane & 15);
        af[i] = *(const f16x8*)(As + row * 64 + ((cg ^ (row & 7)) << 3));
      }
#pragma unroll
      for (int j = 0; j < 4; ++j) {
        const int row = wn * 64 + j * 16 + (lane & 15);
        bf[j] = *(const f16x8*)(Bs + row * 64 + ((cg ^ (row & 7)) << 3));
      }
#pragma unroll
      for (int i = 0; i < 4; ++i)
#pragma unroll
        for (int j = 0; j < 4; ++j)
          acc[i][j] = __builtin_amdgcn_mfma_f32_16x16x32_f16(af[i], bf[j], acc[i][j], 0, 0, 0);
    }
    __syncthreads();
  }

  const long long cb = (long long)bz * sC;
  const int lr = ((lane >> 4) << 2);
  const int lc = lane & 15;
#pragma unroll
  for (int i = 0; i < 4; ++i) {
#pragma unroll
    for (int j = 0; j < 4; ++j) {
      const int col = n0 + wn * 64 + j * 16 + lc;
      const float bv = bias ? bias[col] : 0.0f;
      if (mode == 2 || (mode == 3 && col >= 1024)) {
        // transposed f16 store into vt[b][d][t]
        const int rowb = m0 + wm * 64 + i * 16 + lr;  // 4 consecutive tokens
        const int b = rowb >> 11, t = rowb & 2047;
        const int d = (mode == 3) ? (col - 1024) : col;
        f16* dst = (f16*)((mode == 3) ? Cout2 : Cout);
        f16x4v pk;
#pragma unroll
        for (int r = 0; r < 4; ++r) pk[r] = (f16)(acc[i][j][r] * scale + bv);
        *(f16x4v*)(dst + ((long long)b << 20) + (long long)d * 2048 + t) = pk;
      } else {
#pragma unroll
        for (int r = 0; r < 4; ++r) {
          const int row = m0 + wm * 64 + i * 16 + lr + r;
          float v = acc[i][j][r] * scale + bv;
          if (mode == 0)
            ((float*)Cout)[cb + (long long)row * ldc + col] = v;
          else
            ((f16*)Cout)[cb + (long long)row * ldc + col] = (f16)v;
        }
      }
    }
  }
}

// ---------------- row softmax, wave-per-row, register-resident ----------------
// Only touches cols < ceil128(len): PV reads at most ceil64(len) <= ceil128(len).
__global__ __launch_bounds__(256) void softmax_rows_kernel(f16* __restrict__ sc,
                                                           const int* __restrict__ lens) {
  const int tid = threadIdx.x;
  const int lane = tid & 63;
  const int row = blockIdx.x * 4 + (tid >> 6);
  const int len = lens[row >> 11];
  const int cl = (len + 127) & ~127;
  if ((row & 2047) >= cl) return;  // row never read downstream
  f16* p = sc + (long long)row * S_;

  f16x8 v[4];
#pragma unroll
  for (int c = 0; c < 4; ++c)
    if (c * 512 < cl) v[c] = *(const f16x8*)(p + c * 512 + lane * 8);

  float m = -1e30f;
#pragma unroll
  for (int c = 0; c < 4; ++c) {
    if (c * 512 >= cl) continue;
#pragma unroll
    for (int j = 0; j < 8; ++j) {
      const int col = c * 512 + lane * 8 + j;
      if (col < len) m = fmaxf(m, (float)v[c][j]);
    }
  }
#pragma unroll
  for (int o = 32; o > 0; o >>= 1) m = fmaxf(m, __shfl_xor(m, o, 64));

  float e[32];
  float s = 0.0f;
#pragma unroll
  for (int c = 0; c < 4; ++c) {
    if (c * 512 >= cl) continue;
#pragma unroll
    for (int j = 0; j < 8; ++j) {
      const int col = c * 512 + lane * 8 + j;
      const float x = (col < len) ? __expf((float)v[c][j] - m) : 0.0f;
      e[c * 8 + j] = x;
      s += x;
    }
  }
#pragma unroll
  for (int o = 32; o > 0; o >>= 1) s += __shfl_xor(s, o, 64);
  const float inv = 1.0f / s;

#pragma unroll
  for (int c = 0; c < 4; ++c) {
    if (c * 512 >= cl) continue;
    f16x8 w;
#pragma unroll
    for (int j = 0; j < 8; ++j) w[j] = (f16)(e[c * 8 + j] * inv);
    *(f16x8*)(p + c * 512 + lane * 8) = w;
  }
}

// ---------------- LayerNorm + ReLU + dot(W2) -> ts (fp32) and out_ts (fp32, masked)
__global__ __launch_bounds__(256) void ln_score_kernel(
    const float* __restrict__ h, const int* __restrict__ lens,
    const float* __restrict__ g, const float* __restrict__ bt,
    const float* __restrict__ W2, const float* __restrict__ b2,
    float* __restrict__ ts, float* __restrict__ out_ts) {
  const int token = blockIdx.x;
  const int tid = threadIdx.x;
  const int b = token >> 11, s = token & (S_ - 1);
  if (s >= lens[b]) {  // invalid token: nothing downstream reads ts here
    if (tid == 0) { ts[token] = -10000.0f; out_ts[token] = -10000.0f; }
    return;
  }
  const float* hp = h + (long long)token * D_;
  float x0 = hp[tid], x1 = hp[tid + 256];
  __shared__ float r1[256], r2[256];
  r1[tid] = x0 + x1;
  r2[tid] = x0 * x0 + x1 * x1;
  __syncthreads();
  for (int o = 128; o > 0; o >>= 1) {
    if (tid < o) { r1[tid] += r1[tid + o]; r2[tid] += r2[tid + o]; }
    __syncthreads();
  }
  const float mu = r1[0] * (1.0f / D_);
  const float var = r2[0] * (1.0f / D_) - mu * mu;
  const float rs = rsqrtf(var + 1e-5f);
  float y0 = fmaxf((x0 - mu) * rs * g[tid] + bt[tid], 0.0f);
  float y1 = fmaxf((x1 - mu) * rs * g[tid + 256] + bt[tid + 256], 0.0f);
  float d = y0 * W2[tid] + y1 * W2[tid + 256];
  __syncthreads();
  r1[tid] = d;
  __syncthreads();
  for (int o = 128; o > 0; o >>= 1) {
    if (tid < o) r1[tid] += r1[tid + o];
    __syncthreads();
  }
  if (tid == 0) {
    float v = r1[0] + b2[0];
    ts[token] = v;
    out_ts[token] = v;
  }
}

// ---------------- rationale: cumsum + window argmax (ref tie-break) + span mask
__global__ __launch_bounds__(256) void rationale_kernel(
    const float* __restrict__ ts, const int* __restrict__ lens,
    float* __restrict__ out_rat, int* __restrict__ span) {
  const int b = blockIdx.x;
  const int tid = threadIdx.x;
  const int len = lens[b];
  __shared__ float cum[S_];
  __shared__ float rbest[256];
  __shared__ int ridx[256];

  for (int s = tid; s < S_; s += 256)
    cum[s] = (s < len) ? ts[b * S_ + s] : -10000.0f;
  __syncthreads();
  if (tid == 0) {
    // sequential fp32 cumsum (exact np order) with register dependent-chain
    float a = 0.0f;
    for (int s = 0; s < S_; s += 4) {
      float4 v = *(float4*)(cum + s);
      a += v.x; v.x = a;
      a += v.y; v.y = a;
      a += v.z; v.z = a;
      a += v.w; v.w = a;
      *(float4*)(cum + s) = v;
    }
  }
  __syncthreads();

  float best = -3.4e38f;
  int bidx = 0x7fffffff;
  for (int idx = tid; idx < 18 * S_; idx += 256) {
    const int l = idx >> 11;
    const int s = idx & (S_ - 1);
    const int L = l + 3;
    if (L <= len && s <= len - L) {
      // NOTE: reference uses the PREFIX sum cum[s+L-1]/L (not the window sum)
      const float gv = cum[s + L - 1] / (float)L + 0.01f * ((float)L / 20.0f);
      if (gv > best) { best = gv; bidx = idx; }  // strict >: smallest idx within thread
    }
  }
  rbest[tid] = best;
  ridx[tid] = bidx;
  __syncthreads();
  for (int o = 128; o > 0; o >>= 1) {
    if (tid < o) {
      if (rbest[tid + o] > rbest[tid] ||
          (rbest[tid + o] == rbest[tid] && ridx[tid + o] < ridx[tid])) {
        rbest[tid] = rbest[tid + o];
        ridx[tid] = ridx[tid + o];
      }
    }
    __syncthreads();
  }
  const int bi = ridx[0];
  int start, sl;
  if (len <= 3) { start = 0; sl = len; }  // short-circuit case
  else { start = bi & (S_ - 1); sl = (bi >> 11) + 3; }
  if (tid == 0) { span[2 * b] = start; span[2 * b + 1] = sl; }
  for (int s = tid; s < S_; s += 256)
    out_rat[b * S_ + s] = (s >= start && s < start + sl) ? 1.0f : 0.0f;
}

// ---------------- token_probs: softmax over masked token scores (per batch) ----------------
__global__ __launch_bounds__(256) void tprobs_kernel(const float* __restrict__ ts,
                                                     const int* __restrict__ lens,
                                                     float* __restrict__ out) {
  const int b = blockIdx.x;
  const int tid = threadIdx.x;
  const int len = lens[b];
  const float* p = ts + b * S_;
  __shared__ float r[256];
  float m = -1e30f;
  for (int c = tid; c < len; c += 256) m = fmaxf(m, p[c]);
  r[tid] = m;
  __syncthreads();
  for (int o = 128; o > 0; o >>= 1) {
    if (tid < o) r[tid] = fmaxf(r[tid], r[tid + o]);
    __syncthreads();
  }
  m = r[0];
  __syncthreads();
  float s = 0.0f;
  for (int c = tid; c < len; c += 256) s += expf(p[c] - m);
  r[tid] = s;
  __syncthreads();
  for (int o = 128; o > 0; o >>= 1) {
    if (tid < o) r[tid] += r[tid + o];
    __syncthreads();
  }
  const float inv = 1.0f / r[0];
  for (int c = tid; c < S_; c += 256)
    out[b * S_ + c] = (c < len) ? expf(p[c] - m) * inv : 0.0f;
}

// ---------------- attended = hs * rationale (fp32 out; loads only in-span) ----------------
__global__ __launch_bounds__(256) void attended_kernel(const float4* __restrict__ hs,
                                                       const int* __restrict__ span,
                                                       float4* __restrict__ out) {
  long long i = (long long)blockIdx.x * 256 + threadIdx.x;  // over B*S*H/4
  const int token = (int)(i >> 8);  // / (H_/4)
  const int b = token >> 11;
  const int s = token & (S_ - 1);
  const int st = span[2 * b], ln = span[2 * b + 1];
  float4 v = {0.0f, 0.0f, 0.0f, 0.0f};
  if (s >= st && s < st + ln) v = hs[i];
  out[i] = v;
}

// ---------------- pooled = sum over span / (len + 1e-6) (fp32 out) ----------------
__global__ __launch_bounds__(256) void pooled_kernel(const float* __restrict__ hs,
                                                     const int* __restrict__ span,
                                                     float* __restrict__ out) {
  const int b = blockIdx.x;
  const int tid = threadIdx.x;
  const int st = span[2 * b], ln = span[2 * b + 1];
  const float inv = 1.0f / ((float)ln + 1e-6f);
  for (int h = tid; h < H_; h += 256) {
    float s = 0.0f;
    for (int t = st; t < st + ln; ++t)
      s += hs[(long long)(b * S_ + t) * H_ + h];
    out[b * H_ + h] = s * inv;
  }
}

// ---------------- launch ----------------
extern "C" void kernel_launch(void* const* d_in, const int* in_sizes, int n_in,
                              void* d_out, int out_size, void* d_ws, size_t ws_size,
                              hipStream_t stream) {
  const float* hs = (const float*)d_in[0];
  const int* amask = (const int*)d_in[1];
  const float* Wq = (const float*)d_in[2];
  const float* bq = (const float*)d_in[3];
  const float* Wk = (const float*)d_in[4];
  const float* bk = (const float*)d_in[5];
  const float* W1 = (const float*)d_in[6];
  const float* b1 = (const float*)d_in[7];
  const float* ln_g = (const float*)d_in[8];
  const float* ln_b = (const float*)d_in[9];
  const float* W2 = (const float*)d_in[10];
  const float* b2 = (const float*)d_in[11];

  float* out = (float*)d_out;  // reference outputs are float32
  char* ws = (char*)d_ws;

  // workspace layout (bytes)
  const long long off_hs16 = 0;           // 67,108,864  (fp16 hs; later reused as fp32 h)
  const long long off_qk = 67108864;      // 67,108,864  (32768 x 1024 fp16: [Q|K])
  const long long off_vt = 134217728;     // 33,554,432  (vt[b][d][t] fp16)
  const long long off_wt = 167772160;     // 3,145,728
  const long long off_bias = 170917888;   // 8,192 (bias_full: 1536 floats)
  const long long off_ts = 170926080;     // 131,072
  const long long off_lens = 171057152;   // 64
  const long long off_span = 171057216;   // 192
  const long long off_scores = 171057408; // nb * 8,388,608

  f16* hs16 = (f16*)(ws + off_hs16);
  float* hbuf = (float*)(ws + off_hs16);  // alias: hs16 dead after QKV GEMM
  f16* qk16 = (f16*)(ws + off_qk);
  f16* vt = (f16*)(ws + off_vt);
  f16* Wt = (f16*)(ws + off_wt);
  float* bias_full = (float*)(ws + off_bias);
  float* ts = (float*)(ws + off_ts);
  int* lens = (int*)(ws + off_lens);
  int* span = (int*)(ws + off_span);
  f16* scores = (f16*)(ws + off_scores);

  // adaptive batch-chunking of the scores buffer to fit ws_size
  const long long SC_PER_B = (long long)S_ * S_ * 2;  // 8,388,608 B
  int nb = 16;
  while (nb > 1 && off_scores + (long long)nb * SC_PER_B > (long long)ws_size) nb >>= 1;

  // output sections (fp32 elements)
  float* out_ts = out;                  // 16*2048
  float* out_rat = out + 32768;         // 16*2048
  float* out_tp = out + 65536;          // 16*2048
  float4* out_att = (float4*)(out + 98304);  // 16*2048*1024
  float* out_pool = out + 33652736;     // 16*1024

  setup_kernel<<<dim3(6166), dim3(256), 0, stream>>>(Wq, Wk, W1, bq, bk, b1, amask,
                                                     Wt, bias_full, lens);
  cvt_hs_kernel<<<dim3(32768), dim3(256), 0, stream>>>((const float4*)hs, (f16x4v*)hs16);

  // fused QKV: (32768 x 1536) = hs16 @ Wt^T; cols<1024 -> qk16 (+[bq|bk]),
  // cols>=1024 -> V+b1 transposed into vt[b][d][t]; skip token blocks >= len
  gemm_bt<2><<<dim3(12, 256, 1), dim3(256), 0, stream>>>(
      hs16, Wt, (void*)qk16, (void*)vt, 1024, 1024, 1024, 1024,
      0LL, 0LL, 0LL, 1.0f, bias_full, 3, lens, 1, 8);

  const int chunks = 16 / nb;
  for (int c = 0; c < chunks; ++c) {
    const int b0 = c * nb;
    // scores: per batch (2048x2048) = Q @ K^T / sqrt(512), fp16; skip dead m/n blocks
    gemm_bt<4><<<dim3(16, 16, nb), dim3(256), 0, stream>>>(
        qk16 + (long long)b0 * S_ * 1024,
        qk16 + (long long)b0 * S_ * 1024 + 512,
        (void*)scores, (void*)nullptr, 512, 1024, 1024, 2048,
        (long long)S_ * 1024, (long long)S_ * 1024, (long long)S_ * S_,
        0.044194173824159216f /* 1/sqrt(512) */, (const float*)nullptr, 1,
        lens + b0, 2 | 4, 8);
    softmax_rows_kernel<<<dim3(nb * S_ / 4), dim3(256), 0, stream>>>(scores, lens + b0);
    // h: per batch (2048x512) = P @ V (b1 folded into V; P rows sum to 1);
    // skip dead row blocks, clamp K to ceil64(len); mgrp=1 keeps the 512KB
    // A-tile (P) L2-hot across its 4-n-tile sweep
    gemm_bt<4><<<dim3(4, 16, nb), dim3(256), 0, stream>>>(
        scores, vt + ((long long)b0 << 20),
        (void*)(hbuf + (long long)b0 * S_ * D_), (void*)nullptr, 2048, 2048, 2048, 512,
        (long long)S_ * S_, 1LL << 20, (long long)S_ * D_,
        1.0f, (const float*)nullptr, 0, lens + b0, 2 | 8, 1);
  }

  ln_score_kernel<<<dim3(B_ * S_), dim3(256), 0, stream>>>(hbuf, lens, ln_g, ln_b,
                                                           W2, b2, ts, out_ts);
  rationale_kernel<<<dim3(B_), dim3(256), 0, stream>>>(ts, lens, out_rat, span);
  tprobs_kernel<<<dim3(B_), dim3(256), 0, stream>>>(ts, lens, out_tp);
  attended_kernel<<<dim3(32768), dim3(256), 0, stream>>>((const float4*)hs, span, out_att);
  pooled_kernel<<<dim3(B_), dim3(256), 0, stream>>>(hs, span, out_pool);
}

// Round 6
// 634.193 us; speedup vs baseline: 1.4239x; 1.0527x over previous
//
#include <hip/hip_runtime.h>

typedef _Float16 f16;
typedef __attribute__((ext_vector_type(8))) _Float16 f16x8;
typedef __attribute__((ext_vector_type(4))) _Float16 f16x4v;
typedef __attribute__((ext_vector_type(4))) float f32x4;

#define B_ 16
#define S_ 2048
#define H_ 1024
#define D_ 512

// async 16B global->LDS; lds dest is wave-uniform base + lane*16
__device__ __forceinline__ void gload16(const f16* g, f16* l) {
  __builtin_amdgcn_global_load_lds(
      (const __attribute__((address_space(1))) unsigned int*)g,
      (__attribute__((address_space(3))) unsigned int*)l, 16, 0, 0);
}

// ---------------- fused setup: cvt hs->f16 (live tokens only) + Wt + bias + lens
__global__ __launch_bounds__(256) void setup_cvt_kernel(
    const float4* __restrict__ hs4, const int* __restrict__ mask,
    const float* __restrict__ Wq, const float* __restrict__ Wk,
    const float* __restrict__ W1, const float* __restrict__ bq,
    const float* __restrict__ bk, const float* __restrict__ b1,
    f16x4v* __restrict__ hs16, f16* __restrict__ Wt,
    float* __restrict__ bias, int* __restrict__ lens) {
  const int blk = blockIdx.x;
  const int tid = threadIdx.x;
  if (blk < 32768) {
    // one token per block; dead tokens skipped (garbage rows are finite and
    // only ever multiplied into masked-out outputs)
    if (mask[blk] == 0) return;
    long long i = (long long)blk * 256 + tid;
    float4 v = hs4[i];
    f16x4v o = {(f16)v.x, (f16)v.y, (f16)v.z, (f16)v.w};
    hs16[i] = o;
  } else if (blk < 32768 + 6144) {
    int i = (blk - 32768) * 256 + tid;
    int n = i >> 10;
    int k = i & 1023;
    const float* src = (n < 512) ? Wq : ((n < 1024) ? Wk : W1);
    Wt[i] = (f16)src[k * 512 + (n & 511)];
  } else if (blk < 32768 + 6150) {
    int i = (blk - 32768 - 6144) * 256 + tid;
    if (i < 1536) bias[i] = (i < 512) ? bq[i] : ((i < 1024) ? bk[i - 512] : b1[i - 1024]);
  } else {
    int b = blk - 32768 - 6150;  // 0..15
    int s = 0;
    for (int c = tid; c < S_; c += 256) s += mask[b * S_ + c];
    __shared__ int r[256];
    r[tid] = s;
    __syncthreads();
    for (int o = 128; o > 0; o >>= 1) {
      if (tid < o) r[tid] += r[tid + o];
      __syncthreads();
    }
    if (tid == 0) lens[b] = r[0];
  }
}

// ---------------- GEMM: C[m][n] = scale * (sum_k A[m][k]*Bt[n][k]) + bias[n]
// 128x128 tile, BK=64, mfma_f32_16x16x32_f16, async global_load_lds staging,
// XOR-swizzled LDS (zero bank conflicts, verified R3), mgrp-sized m-tile-group
// dispatch order for A-tile L2 residency (verified R4: FETCH 204->126MB).
// MW template arg = min waves/SIMD (4 => <=128 regs/wave; verified R5 win).
// mode: 0=f32 store, 1=f16 store, 2=f16 transposed store into vt[b][d][t],
//       3=fused QKV: col<1024 -> Cout (qk16), col>=1024 -> Cout2 (vt, transposed)
// lflags: 1 = len from lens[m0>>11], skip block if (m0&2047) >= len  (QKV)
//         2 = len from lens[bz], skip if (m0&2047) >= len            (scores/PV)
//         4 = skip if n0 >= len                                      (scores)
//         8 = clamp K to ceil64(len)                                 (PV)
template <int MW>
__global__ __launch_bounds__(256, MW) void gemm_bt(
    const f16* __restrict__ A, const f16* __restrict__ Bm, void* __restrict__ Cout,
    void* __restrict__ Cout2,
    int K, int lda, int ldb, int ldc,
    long long sA, long long sB, long long sC,
    float scale, const float* __restrict__ bias, int mode,
    const int* __restrict__ lens, int lflags, int mgrp) {
  const int bz = blockIdx.z;

  // ---- block swizzle: A-tile-group-major dispatch order (bijective remap)
  const int ntiles = gridDim.x, mtiles = gridDim.y;
  const int flat = blockIdx.y * ntiles + blockIdx.x;
  const int per = mgrp * ntiles;
  const int grp = flat / per;
  const int rem = flat - grp * per;
  const int gbase = grp * mgrp;
  int gsz = mtiles - gbase;
  if (gsz > mgrp) gsz = mgrp;
  const int mt = gbase + rem % gsz;
  const int nt = rem / gsz;
  const int m0 = mt * 128;
  const int n0 = nt * 128;

  int Keff = K;
  if (lflags) {
    const int len = lens[(lflags & 1) ? (m0 >> 11) : bz];
    if ((lflags & 3) && (m0 & 2047) >= len) return;
    if ((lflags & 4) && n0 >= len) return;
    if (lflags & 8) { int kl = (len + 63) & ~63; Keff = kl < K ? kl : K; }
  }

  A += (long long)bz * sA;
  Bm += (long long)bz * sB;

  __shared__ f16 As[128 * 64];
  __shared__ f16 Bs[128 * 64];

  const int tid = threadIdx.x;
  const int lane = tid & 63;
  const int wid = tid >> 6;
  const int wm = wid & 1, wn = wid >> 1;

  f32x4 acc[4][4] = {};

  const int lr8 = lane >> 3;  // row within 8-row staging group
  const int sg = lane & 7;    // LDS slot col-group

  for (int k0 = 0; k0 < Keff; k0 += 64) {
#pragma unroll
    for (int it = 0; it < 4; ++it) {
      const int r0 = it * 32 + wid * 8;
      const int r = r0 + lr8;
      const int cg = sg ^ (r & 7);  // source col-group for swizzled slot
      gload16(A + (long long)(m0 + r) * lda + k0 + cg * 8, As + r0 * 64);
      gload16(Bm + (long long)(n0 + r) * ldb + k0 + cg * 8, Bs + r0 * 64);
    }
    __syncthreads();

#pragma unroll
    for (int kk = 0; kk < 64; kk += 32) {
      const int cg = (kk >> 3) + (lane >> 4);
      f16x8 af[4], bf[4];
#pragma unroll
      for (int i = 0; i < 4; ++i) {
        const int row = wm * 64 + i * 16 + (lane & 15);
        af[i] = *(const f16x8*)(As + row * 64 + ((cg ^ (row & 7)) << 3));
      }
#pragma unroll
      for (int j = 0; j < 4; ++j) {
        const int row = wn * 64 + j * 16 + (lane & 15);
        bf[j] = *(const f16x8*)(Bs + row * 64 + ((cg ^ (row & 7)) << 3));
      }
#pragma unroll
      for (int i = 0; i < 4; ++i)
#pragma unroll
        for (int j = 0; j < 4; ++j)
          acc[i][j] = __builtin_amdgcn_mfma_f32_16x16x32_f16(af[i], bf[j], acc[i][j], 0, 0, 0);
    }
    __syncthreads();
  }

  const long long cb = (long long)bz * sC;
  const int lr = ((lane >> 4) << 2);
  const int lc = lane & 15;
#pragma unroll
  for (int i = 0; i < 4; ++i) {
#pragma unroll
    for (int j = 0; j < 4; ++j) {
      const int col = n0 + wn * 64 + j * 16 + lc;
      const float bv = bias ? bias[col] : 0.0f;
      if (mode == 2 || (mode == 3 && col >= 1024)) {
        // transposed f16 store into vt[b][d][t]
        const int rowb = m0 + wm * 64 + i * 16 + lr;  // 4 consecutive tokens
        const int b = rowb >> 11, t = rowb & 2047;
        const int d = (mode == 3) ? (col - 1024) : col;
        f16* dst = (f16*)((mode == 3) ? Cout2 : Cout);
        f16x4v pk;
#pragma unroll
        for (int r = 0; r < 4; ++r) pk[r] = (f16)(acc[i][j][r] * scale + bv);
        *(f16x4v*)(dst + ((long long)b << 20) + (long long)d * 2048 + t) = pk;
      } else {
#pragma unroll
        for (int r = 0; r < 4; ++r) {
          const int row = m0 + wm * 64 + i * 16 + lr + r;
          float v = acc[i][j][r] * scale + bv;
          if (mode == 0)
            ((float*)Cout)[cb + (long long)row * ldc + col] = v;
          else
            ((f16*)Cout)[cb + (long long)row * ldc + col] = (f16)v;
        }
      }
    }
  }
}

// ---------------- row softmax, wave-per-row, register-resident ----------------
// Only touches cols < ceil128(len): PV reads at most ceil64(len) <= ceil128(len).
__global__ __launch_bounds__(256) void softmax_rows_kernel(f16* __restrict__ sc,
                                                           const int* __restrict__ lens) {
  const int tid = threadIdx.x;
  const int lane = tid & 63;
  const int row = blockIdx.x * 4 + (tid >> 6);
  const int len = lens[row >> 11];
  const int cl = (len + 127) & ~127;
  if ((row & 2047) >= cl) return;  // row never read downstream
  f16* p = sc + (long long)row * S_;

  f16x8 v[4];
#pragma unroll
  for (int c = 0; c < 4; ++c)
    if (c * 512 < cl) v[c] = *(const f16x8*)(p + c * 512 + lane * 8);

  float m = -1e30f;
#pragma unroll
  for (int c = 0; c < 4; ++c) {
    if (c * 512 >= cl) continue;
#pragma unroll
    for (int j = 0; j < 8; ++j) {
      const int col = c * 512 + lane * 8 + j;
      if (col < len) m = fmaxf(m, (float)v[c][j]);
    }
  }
#pragma unroll
  for (int o = 32; o > 0; o >>= 1) m = fmaxf(m, __shfl_xor(m, o, 64));

  float e[32];
  float s = 0.0f;
#pragma unroll
  for (int c = 0; c < 4; ++c) {
    if (c * 512 >= cl) continue;
#pragma unroll
    for (int j = 0; j < 8; ++j) {
      const int col = c * 512 + lane * 8 + j;
      const float x = (col < len) ? __expf((float)v[c][j] - m) : 0.0f;
      e[c * 8 + j] = x;
      s += x;
    }
  }
#pragma unroll
  for (int o = 32; o > 0; o >>= 1) s += __shfl_xor(s, o, 64);
  const float inv = 1.0f / s;

#pragma unroll
  for (int c = 0; c < 4; ++c) {
    if (c * 512 >= cl) continue;
    f16x8 w;
#pragma unroll
    for (int j = 0; j < 8; ++j) w[j] = (f16)(e[c * 8 + j] * inv);
    *(f16x8*)(p + c * 512 + lane * 8) = w;
  }
}

// ---------------- LayerNorm + ReLU + dot(W2): wave-per-token, no barriers ----------------
__global__ __launch_bounds__(256) void ln_score_kernel(
    const float* __restrict__ h, const int* __restrict__ lens,
    const float* __restrict__ g, const float* __restrict__ bt,
    const float* __restrict__ W2, const float* __restrict__ b2,
    float* __restrict__ ts, float* __restrict__ out_ts) {
  const int tid = threadIdx.x;
  const int lane = tid & 63;
  const int token = blockIdx.x * 4 + (tid >> 6);
  const int b = token >> 11, s = token & (S_ - 1);
  if (s >= lens[b]) {  // invalid token: nothing downstream reads ts here
    if (lane == 0) { ts[token] = -10000.0f; out_ts[token] = -10000.0f; }
    return;
  }
  const float* hp = h + (long long)token * D_;
  const int o8 = lane * 8;
  float4 xa = *(const float4*)(hp + o8);
  float4 xb = *(const float4*)(hp + o8 + 4);
  float s1 = xa.x + xa.y + xa.z + xa.w + xb.x + xb.y + xb.z + xb.w;
  float s2 = xa.x * xa.x + xa.y * xa.y + xa.z * xa.z + xa.w * xa.w +
             xb.x * xb.x + xb.y * xb.y + xb.z * xb.z + xb.w * xb.w;
#pragma unroll
  for (int o = 32; o > 0; o >>= 1) {
    s1 += __shfl_xor(s1, o, 64);
    s2 += __shfl_xor(s2, o, 64);
  }
  const float mu = s1 * (1.0f / D_);
  const float var = s2 * (1.0f / D_) - mu * mu;
  const float rs = rsqrtf(var + 1e-5f);
  float4 ga = *(const float4*)(g + o8), gb = *(const float4*)(g + o8 + 4);
  float4 ba = *(const float4*)(bt + o8), bb = *(const float4*)(bt + o8 + 4);
  float4 wa = *(const float4*)(W2 + o8), wb = *(const float4*)(W2 + o8 + 4);
  float d = 0.0f;
  d += fmaxf((xa.x - mu) * rs * ga.x + ba.x, 0.0f) * wa.x;
  d += fmaxf((xa.y - mu) * rs * ga.y + ba.y, 0.0f) * wa.y;
  d += fmaxf((xa.z - mu) * rs * ga.z + ba.z, 0.0f) * wa.z;
  d += fmaxf((xa.w - mu) * rs * ga.w + ba.w, 0.0f) * wa.w;
  d += fmaxf((xb.x - mu) * rs * gb.x + bb.x, 0.0f) * wb.x;
  d += fmaxf((xb.y - mu) * rs * gb.y + bb.y, 0.0f) * wb.y;
  d += fmaxf((xb.z - mu) * rs * gb.z + bb.z, 0.0f) * wb.z;
  d += fmaxf((xb.w - mu) * rs * gb.w + bb.w, 0.0f) * wb.w;
#pragma unroll
  for (int o = 32; o > 0; o >>= 1) d += __shfl_xor(d, o, 64);
  if (lane == 0) {
    float v = d + b2[0];
    ts[token] = v;
    out_ts[token] = v;
  }
}

// ---------------- fused rationale (cumsum + argmax + span) and token_probs ----------------
__global__ __launch_bounds__(256) void rat_tprobs_kernel(
    const float* __restrict__ ts, const int* __restrict__ lens,
    float* __restrict__ out_rat, float* __restrict__ out_tp,
    int* __restrict__ span) {
  const int b = blockIdx.x;
  const int tid = threadIdx.x;
  const int len = lens[b];
  __shared__ float cum[S_];
  __shared__ float rbest[256];
  __shared__ int ridx[256];

  for (int s = tid; s < S_; s += 256)
    cum[s] = (s < len) ? ts[b * S_ + s] : -10000.0f;
  __syncthreads();
  if (tid == 0) {
    // sequential fp32 cumsum (exact np order) with register dependent-chain
    float a = 0.0f;
    for (int s = 0; s < S_; s += 4) {
      float4 v = *(float4*)(cum + s);
      a += v.x; v.x = a;
      a += v.y; v.y = a;
      a += v.z; v.z = a;
      a += v.w; v.w = a;
      *(float4*)(cum + s) = v;
    }
  }
  __syncthreads();

  float best = -3.4e38f;
  int bidx = 0x7fffffff;
  for (int idx = tid; idx < 18 * S_; idx += 256) {
    const int l = idx >> 11;
    const int s = idx & (S_ - 1);
    const int L = l + 3;
    if (L <= len && s <= len - L) {
      // NOTE: reference uses the PREFIX sum cum[s+L-1]/L (not the window sum)
      const float gv = cum[s + L - 1] / (float)L + 0.01f * ((float)L / 20.0f);
      if (gv > best) { best = gv; bidx = idx; }  // strict >: smallest idx within thread
    }
  }
  rbest[tid] = best;
  ridx[tid] = bidx;
  __syncthreads();
  for (int o = 128; o > 0; o >>= 1) {
    if (tid < o) {
      if (rbest[tid + o] > rbest[tid] ||
          (rbest[tid + o] == rbest[tid] && ridx[tid + o] < ridx[tid])) {
        rbest[tid] = rbest[tid + o];
        ridx[tid] = ridx[tid + o];
      }
    }
    __syncthreads();
  }
  const int bi = ridx[0];
  int start, sl;
  if (len <= 3) { start = 0; sl = len; }  // short-circuit case
  else { start = bi & (S_ - 1); sl = (bi >> 11) + 3; }
  if (tid == 0) { span[2 * b] = start; span[2 * b + 1] = sl; }
  for (int s = tid; s < S_; s += 256)
    out_rat[b * S_ + s] = (s >= start && s < start + sl) ? 1.0f : 0.0f;

  // ---- token_probs phase (re-reads ts; L2-hot)
  __syncthreads();
  const float* p = ts + b * S_;
  float m = -1e30f;
  for (int c = tid; c < len; c += 256) m = fmaxf(m, p[c]);
  rbest[tid] = m;
  __syncthreads();
  for (int o = 128; o > 0; o >>= 1) {
    if (tid < o) rbest[tid] = fmaxf(rbest[tid], rbest[tid + o]);
    __syncthreads();
  }
  m = rbest[0];
  __syncthreads();
  float sm = 0.0f;
  for (int c = tid; c < len; c += 256) sm += expf(p[c] - m);
  rbest[tid] = sm;
  __syncthreads();
  for (int o = 128; o > 0; o >>= 1) {
    if (tid < o) rbest[tid] += rbest[tid + o];
    __syncthreads();
  }
  const float inv = 1.0f / rbest[0];
  for (int c = tid; c < S_; c += 256)
    out_tp[b * S_ + c] = (c < len) ? expf(p[c] - m) * inv : 0.0f;
}

// ---------------- fused attended (span-masked copy) + pooled (span mean) ----------------
__global__ __launch_bounds__(256) void att_pool_kernel(
    const float4* __restrict__ hs4, const float* __restrict__ hs,
    const int* __restrict__ span, float4* __restrict__ out_att,
    float* __restrict__ out_pool) {
  const int blk = blockIdx.x;
  const int tid = threadIdx.x;
  if (blk < 32768) {
    long long i = (long long)blk * 256 + tid;  // over B*S*H/4
    const int token = (int)(i >> 8);
    const int b = token >> 11;
    const int s = token & (S_ - 1);
    const int st = span[2 * b], ln = span[2 * b + 1];
    float4 v = {0.0f, 0.0f, 0.0f, 0.0f};
    if (s >= st && s < st + ln) v = hs4[i];
    out_att[i] = v;
  } else {
    const int b = blk - 32768;
    const int st = span[2 * b], ln = span[2 * b + 1];
    const float inv = 1.0f / ((float)ln + 1e-6f);
    for (int h = tid; h < H_; h += 256) {
      float s = 0.0f;
      for (int t = st; t < st + ln; ++t)
        s += hs[(long long)(b * S_ + t) * H_ + h];
      out_pool[b * H_ + h] = s * inv;
    }
  }
}

// ---------------- launch ----------------
extern "C" void kernel_launch(void* const* d_in, const int* in_sizes, int n_in,
                              void* d_out, int out_size, void* d_ws, size_t ws_size,
                              hipStream_t stream) {
  const float* hs = (const float*)d_in[0];
  const int* amask = (const int*)d_in[1];
  const float* Wq = (const float*)d_in[2];
  const float* bq = (const float*)d_in[3];
  const float* Wk = (const float*)d_in[4];
  const float* bk = (const float*)d_in[5];
  const float* W1 = (const float*)d_in[6];
  const float* b1 = (const float*)d_in[7];
  const float* ln_g = (const float*)d_in[8];
  const float* ln_b = (const float*)d_in[9];
  const float* W2 = (const float*)d_in[10];
  const float* b2 = (const float*)d_in[11];

  float* out = (float*)d_out;  // reference outputs are float32
  char* ws = (char*)d_ws;

  // workspace layout (bytes)
  const long long off_hs16 = 0;           // 67,108,864  (fp16 hs; later reused as fp32 h)
  const long long off_qk = 67108864;      // 67,108,864  (32768 x 1024 fp16: [Q|K])
  const long long off_vt = 134217728;     // 33,554,432  (vt[b][d][t] fp16)
  const long long off_wt = 167772160;     // 3,145,728
  const long long off_bias = 170917888;   // 8,192 (bias_full: 1536 floats)
  const long long off_ts = 170926080;     // 131,072
  const long long off_lens = 171057152;   // 64
  const long long off_span = 171057216;   // 192
  const long long off_scores = 171057408; // nb * 8,388,608

  f16* hs16 = (f16*)(ws + off_hs16);
  float* hbuf = (float*)(ws + off_hs16);  // alias: hs16 dead after QKV GEMM
  f16* qk16 = (f16*)(ws + off_qk);
  f16* vt = (f16*)(ws + off_vt);
  f16* Wt = (f16*)(ws + off_wt);
  float* bias_full = (float*)(ws + off_bias);
  float* ts = (float*)(ws + off_ts);
  int* lens = (int*)(ws + off_lens);
  int* span = (int*)(ws + off_span);
  f16* scores = (f16*)(ws + off_scores);

  // adaptive batch-chunking of the scores buffer to fit ws_size
  const long long SC_PER_B = (long long)S_ * S_ * 2;  // 8,388,608 B
  int nb = 16;
  while (nb > 1 && off_scores + (long long)nb * SC_PER_B > (long long)ws_size) nb >>= 1;

  // output sections (fp32 elements)
  float* out_ts = out;                  // 16*2048
  float* out_rat = out + 32768;         // 16*2048
  float* out_tp = out + 65536;          // 16*2048
  float4* out_att = (float4*)(out + 98304);  // 16*2048*1024
  float* out_pool = out + 33652736;     // 16*1024

  // 1) fused setup + convert (dead tokens skipped)
  setup_cvt_kernel<<<dim3(32768 + 6144 + 6 + 16), dim3(256), 0, stream>>>(
      (const float4*)hs, amask, Wq, Wk, W1, bq, bk, b1,
      (f16x4v*)hs16, Wt, bias_full, lens);

  // 2) fused QKV: (32768 x 1536) = hs16 @ Wt^T; cols<1024 -> qk16 (+[bq|bk]),
  //    cols>=1024 -> V+b1 transposed into vt[b][d][t]; skip token blocks >= len
  gemm_bt<2><<<dim3(12, 256, 1), dim3(256), 0, stream>>>(
      hs16, Wt, (void*)qk16, (void*)vt, 1024, 1024, 1024, 1024,
      0LL, 0LL, 0LL, 1.0f, bias_full, 3, lens, 1, 8);

  const int chunks = 16 / nb;
  for (int c = 0; c < chunks; ++c) {
    const int b0 = c * nb;
    // 3) scores: per batch (2048x2048) = Q @ K^T / sqrt(512), fp16; skip dead m/n blocks
    gemm_bt<4><<<dim3(16, 16, nb), dim3(256), 0, stream>>>(
        qk16 + (long long)b0 * S_ * 1024,
        qk16 + (long long)b0 * S_ * 1024 + 512,
        (void*)scores, (void*)nullptr, 512, 1024, 1024, 2048,
        (long long)S_ * 1024, (long long)S_ * 1024, (long long)S_ * S_,
        0.044194173824159216f /* 1/sqrt(512) */, (const float*)nullptr, 1,
        lens + b0, 2 | 4, 8);
    // 4) softmax over valid prefix
    softmax_rows_kernel<<<dim3(nb * S_ / 4), dim3(256), 0, stream>>>(scores, lens + b0);
    // 5) h: per batch (2048x512) = P @ V (b1 folded into V; P rows sum to 1);
    //    skip dead row blocks, clamp K to ceil64(len); mgrp=1 keeps the P
    //    A-tile L2-hot across its 4-n-tile sweep
    gemm_bt<4><<<dim3(4, 16, nb), dim3(256), 0, stream>>>(
        scores, vt + ((long long)b0 << 20),
        (void*)(hbuf + (long long)b0 * S_ * D_), (void*)nullptr, 2048, 2048, 2048, 512,
        (long long)S_ * S_, 1LL << 20, (long long)S_ * D_,
        1.0f, (const float*)nullptr, 0, lens + b0, 2 | 8, 1);
  }

  // 6) LayerNorm+ReLU+W2 (wave per token)
  ln_score_kernel<<<dim3(B_ * S_ / 4), dim3(256), 0, stream>>>(hbuf, lens, ln_g, ln_b,
                                                               W2, b2, ts, out_ts);
  // 7) rationale + token_probs
  rat_tprobs_kernel<<<dim3(B_), dim3(256), 0, stream>>>(ts, lens, out_rat, out_tp, span);
  // 8) attended + pooled
  att_pool_kernel<<<dim3(32768 + 16), dim3(256), 0, stream>>>(
      (const float4*)hs, hs, span, out_att, out_pool);
}